// Round 2
// baseline (764.663 us; speedup 1.0000x reference)
//
#include <hip/hip_runtime.h>

typedef __bf16 bf16_t;
typedef __bf16 bf16x8 __attribute__((ext_vector_type(8)));
typedef float  f32x4  __attribute__((ext_vector_type(4)));

// XOR-swizzled LDS index for a [64][256] bf16 tile.
__device__ __forceinline__ int swz(int row, int col) {
    return row * 256 + ((((col >> 3) ^ (row & 7)) << 3) | (col & 7));
}

// ---------------------------------------------------------------------------
// BN stats for both inputs in one launch. stats layout: [mu(D), rstd(D)]
__global__ void bn_stats_kernel(const float* __restrict__ xs, const float* __restrict__ us,
                                float* __restrict__ stats_x, float* __restrict__ stats_u) {
    const float* x; int M, D; float* stats;
    if (blockIdx.x == 0) { x = xs; M = 4096; D = 16; stats = stats_x; }
    else                 { x = us; M = 4032; D = 8;  stats = stats_u; }
    __shared__ float s1[256], s2[256];
    int tid = threadIdx.x;
    float a = 0.f, b = 0.f;
    int N = M * D;
    for (int idx = tid; idx < N; idx += 256) {  // 256 % D == 0 keeps col fixed
        float v = x[idx];
        a += v; b += v * v;
    }
    s1[tid] = a; s2[tid] = b;
    __syncthreads();
    if (tid < D) {
        float sa = 0.f, sb = 0.f;
        for (int k = tid; k < 256; k += D) { sa += s1[k]; sb += s2[k]; }
        float mu  = sa / (float)M;
        float var = sb / (float)M - mu * mu;
        stats[tid]     = mu;
        stats[D + tid] = rsqrtf(var + 1e-5f);
    }
}

// Normalize + K-pad to 32 cols, bf16, both inputs in one launch.
__global__ void normalize_kernel(const float* __restrict__ xs, const float* __restrict__ us,
                                 const float* __restrict__ stats_x, const float* __restrict__ stats_u,
                                 bf16_t* __restrict__ Xn, bf16_t* __restrict__ Un) {
    int bx = blockIdx.x;
    const float* x; const float* stats; bf16_t* outp; int M, D, idx;
    if (bx < 512) { x = xs; stats = stats_x; outp = Xn; M = 4096; D = 16; idx = bx * 256 + threadIdx.x; }
    else          { x = us; stats = stats_u; outp = Un; M = 4032; D = 8;  idx = (bx - 512) * 256 + threadIdx.x; }
    if (idx >= M * 32) return;
    int m = idx >> 5, dp = idx & 31;
    float v = 0.f;
    if (dp < D) v = (x[m * D + dp] - stats[dp]) * stats[D + dp];
    outp[idx] = (bf16_t)v;
}

// Fold gamma into W1 (transposed [j][256][32], K-padded, bf16), beta into b1. Both nets.
__global__ __launch_bounds__(256) void prep_w1_kernel(
    const float* __restrict__ xW1, const float* __restrict__ xb1,
    const float* __restrict__ xg,  const float* __restrict__ xbeta,
    const float* __restrict__ uW1, const float* __restrict__ ub1,
    const float* __restrict__ ug,  const float* __restrict__ ubeta,
    bf16_t* __restrict__ xW1t, float* __restrict__ xb1p,
    bf16_t* __restrict__ uW1t, float* __restrict__ ub1p) {
    int bid = blockIdx.x, j = bid & 63, h = threadIdx.x;
    const float *W1, *b1, *gamma, *beta; bf16_t* W1t; float* b1p; int D;
    if (bid < 64) { W1 = xW1; b1 = xb1; gamma = xg; beta = xbeta; W1t = xW1t; b1p = xb1p; D = 16; }
    else          { W1 = uW1; b1 = ub1; gamma = ug; beta = ubeta; W1t = uW1t; b1p = ub1p; D = 8; }
    float bacc = b1[j * 256 + h];
    bf16_t* orow = W1t + (size_t)(j * 256 + h) * 32;
    for (int d = 0; d < 32; d++) orow[d] = (bf16_t)0.f;
    for (int d = 0; d < D; d++) {
        float w = W1[((size_t)j * D + d) * 256 + h];
        orow[d] = (bf16_t)(gamma[j * D + d] * w);
        bacc += beta[j * D + d] * w;
    }
    b1p[j * 256 + h] = bacc;
}

// All four weight transposes (fp32 [64][256][C] -> bf16 [64][C][256]) in one launch.
__global__ __launch_bounds__(256) void transpose_all_kernel(
    const float* __restrict__ xW2, const float* __restrict__ uW2,
    const float* __restrict__ xW3, const float* __restrict__ uW3,
    const float* __restrict__ x_scale, const float* __restrict__ u_scale,
    bf16_t* __restrict__ xW2t, bf16_t* __restrict__ uW2t,
    bf16_t* __restrict__ xW3t, bf16_t* __restrict__ uW3t) {
    __shared__ float tile[32][33];
    int z = blockIdx.z, b = z & 63;
    const float* in; bf16_t* outp; const float* scale = nullptr; int C;
    if (z < 64)       { in = xW2; outp = xW2t; C = 256; }
    else if (z < 128) { in = uW2; outp = uW2t; C = 256; }
    else if (z < 192) { in = xW3; outp = xW3t; scale = x_scale + b * 128; C = 128; if (blockIdx.x >= 4) return; }
    else              { in = uW3; outp = uW3t; scale = u_scale + b * 128; C = 128; if (blockIdx.x >= 4) return; }
    const int R = 256;
    in   += (size_t)b * R * C;
    outp += (size_t)b * R * C;
    int r0 = blockIdx.y * 32, c0 = blockIdx.x * 32;
    int tx = threadIdx.x & 31, ty = threadIdx.x >> 5;
    #pragma unroll
    for (int i = 0; i < 4; i++)
        tile[ty + i * 8][tx] = in[(size_t)(r0 + ty + i * 8) * C + c0 + tx];
    __syncthreads();
    #pragma unroll
    for (int i = 0; i < 4; i++) {
        int c = c0 + ty + i * 8;
        float sc = scale ? scale[c] : 1.f;
        outp[(size_t)c * R + r0 + tx] = (bf16_t)(tile[tx][ty + i * 8] * sc);
    }
}

// ---------------------------------------------------------------------------
// Fused 3-layer MLP, both encoders in one grid (blockIdx.x<64 -> x, else u).
// Single 32KB LDS buffer (h1 -> h2 -> C-stage reuse) for 4 blocks/CU occupancy.
// Output layout: [m][j][128].
__global__ __launch_bounds__(256, 4) void fused_mlp_kernel(
    const bf16_t* __restrict__ Xn, const bf16_t* __restrict__ Un,
    const bf16_t* __restrict__ xW1t, const float* __restrict__ xb1p,
    const bf16_t* __restrict__ xW2t, const float* __restrict__ xb2,
    const bf16_t* __restrict__ xW3t,
    const bf16_t* __restrict__ uW1t, const float* __restrict__ ub1p,
    const bf16_t* __restrict__ uW2t, const float* __restrict__ ub2,
    const bf16_t* __restrict__ uW3t,
    bf16_t* __restrict__ phi, bf16_t* __restrict__ psiu)
{
    const bool is_x = blockIdx.x < 64;
    const int tile  = is_x ? blockIdx.x : (blockIdx.x - 64);
    const bf16_t* In  = is_x ? Xn   : Un;
    const bf16_t* W1t = is_x ? xW1t : uW1t;
    const float*  b1p = is_x ? xb1p : ub1p;
    const bf16_t* W2t = is_x ? xW2t : uW2t;
    const float*  b2  = is_x ? xb2  : ub2;
    const bf16_t* W3t = is_x ? xW3t : uW3t;
    bf16_t* outp      = is_x ? phi  : psiu;

    const int j    = blockIdx.y;
    const int row0 = tile * 64;
    const int tid  = threadIdx.x;
    const int wave = tid >> 6;
    const int lane = tid & 63;
    const int quad = lane >> 4;
    const int l16  = lane & 15;

    __shared__ __align__(16) bf16_t hs[64 * 256];   // 32 KB, reused 3x

    const f32x4 vzero = {0.f, 0.f, 0.f, 0.f};

    // ---------------- layer 1 (K=32, zero-padded) ----------------
    {
        f32x4 acc[4][4];
        #pragma unroll
        for (int a = 0; a < 4; a++)
            #pragma unroll
            for (int c = 0; c < 4; c++) acc[a][c] = vzero;

        bf16x8 afr[4];
        #pragma unroll
        for (int mb = 0; mb < 4; mb++)
            afr[mb] = *reinterpret_cast<const bf16x8*>(
                In + (size_t)(row0 + mb * 16 + l16) * 32 + quad * 8);

        #pragma unroll
        for (int nbi = 0; nbi < 4; nbi++) {
            const int n = (wave * 4 + nbi) * 16 + l16;
            bf16x8 bfr = *reinterpret_cast<const bf16x8*>(
                W1t + (size_t)(j * 256 + n) * 32 + quad * 8);
            #pragma unroll
            for (int mb = 0; mb < 4; mb++)
                acc[mb][nbi] = __builtin_amdgcn_mfma_f32_16x16x32_bf16(
                    afr[mb], bfr, acc[mb][nbi], 0, 0, 0);
        }
        #pragma unroll
        for (int nbi = 0; nbi < 4; nbi++) {
            const int n = (wave * 4 + nbi) * 16 + l16;
            const float bias = b1p[j * 256 + n];
            #pragma unroll
            for (int mb = 0; mb < 4; mb++)
                #pragma unroll
                for (int r = 0; r < 4; r++) {
                    float v = acc[mb][nbi][r] + bias;
                    v = fmaxf(v, 0.01f * v);
                    hs[swz(mb * 16 + quad * 4 + r, n)] = (bf16_t)v;
                }
        }
    }
    __syncthreads();

    // ---------------- layer 2 (256x256), acc in regs, then overwrite hs ------
    {
        f32x4 acc[4][4];
        #pragma unroll
        for (int a = 0; a < 4; a++)
            #pragma unroll
            for (int c = 0; c < 4; c++) acc[a][c] = vzero;

        #pragma unroll
        for (int kk = 0; kk < 8; kk++) {
            bf16x8 av[4];
            #pragma unroll
            for (int mb = 0; mb < 4; mb++) {
                const int row = mb * 16 + l16;
                const int gi  = (kk * 4 + quad) ^ (row & 7);
                av[mb] = *reinterpret_cast<const bf16x8*>(hs + row * 256 + gi * 8);
            }
            #pragma unroll
            for (int nbi = 0; nbi < 4; nbi++) {
                const int n = (wave * 4 + nbi) * 16 + l16;
                bf16x8 bv = *reinterpret_cast<const bf16x8*>(
                    W2t + (size_t)(j * 256 + n) * 256 + kk * 32 + quad * 8);
                #pragma unroll
                for (int mb = 0; mb < 4; mb++)
                    acc[mb][nbi] = __builtin_amdgcn_mfma_f32_16x16x32_bf16(
                        av[mb], bv, acc[mb][nbi], 0, 0, 0);
            }
        }
        __syncthreads();   // all h1 reads done; safe to overwrite
        #pragma unroll
        for (int nbi = 0; nbi < 4; nbi++) {
            const int n = (wave * 4 + nbi) * 16 + l16;
            const float bias = b2[j * 256 + n];
            #pragma unroll
            for (int mb = 0; mb < 4; mb++)
                #pragma unroll
                for (int r = 0; r < 4; r++) {
                    float v = acc[mb][nbi][r] + bias;
                    v = fmaxf(v, 0.01f * v);
                    hs[swz(mb * 16 + quad * 4 + r, n)] = (bf16_t)v;
                }
        }
    }
    __syncthreads();

    // ---------------- layer 3 (256x128, scale folded) ----------------
    {
        f32x4 acc[4][2];
        #pragma unroll
        for (int a = 0; a < 4; a++) { acc[a][0] = vzero; acc[a][1] = vzero; }

        #pragma unroll
        for (int kk = 0; kk < 8; kk++) {
            bf16x8 av[4];
            #pragma unroll
            for (int mb = 0; mb < 4; mb++) {
                const int row = mb * 16 + l16;
                const int gi  = (kk * 4 + quad) ^ (row & 7);
                av[mb] = *reinterpret_cast<const bf16x8*>(hs + row * 256 + gi * 8);
            }
            #pragma unroll
            for (int nbi = 0; nbi < 2; nbi++) {
                const int n = (wave * 2 + nbi) * 16 + l16;
                bf16x8 bv = *reinterpret_cast<const bf16x8*>(
                    W3t + (size_t)(j * 128 + n) * 256 + kk * 32 + quad * 8);
                #pragma unroll
                for (int mb = 0; mb < 4; mb++)
                    acc[mb][nbi] = __builtin_amdgcn_mfma_f32_16x16x32_bf16(
                        av[mb], bv, acc[mb][nbi], 0, 0, 0);
            }
        }
        __syncthreads();   // all h2 reads done; safe to overwrite
        #pragma unroll
        for (int nbi = 0; nbi < 2; nbi++) {
            const int n = (wave * 2 + nbi) * 16 + l16;
            #pragma unroll
            for (int mb = 0; mb < 4; mb++)
                #pragma unroll
                for (int r = 0; r < 4; r++)
                    hs[swz(mb * 16 + quad * 4 + r, n)] = (bf16_t)acc[mb][nbi][r];
        }
    }
    __syncthreads();
    // coalesced global write, layout [m][j][128]
    #pragma unroll
    for (int p = 0; p < 4; p++) {
        const int rr = p * 16 + (tid >> 4);
        const int c8 = (tid & 15) * 8;
        const int gi = (c8 >> 3) ^ (rr & 7);
        bf16x8 v = *reinterpret_cast<const bf16x8*>(hs + rr * 256 + gi * 8);
        *reinterpret_cast<bf16x8*>(outp + ((size_t)(row0 + rr) * 64 + j) * 128 + c8) = v;
    }
}

// ---------------------------------------------------------------------------
// psi(0) per net: xn=0 -> layer1 preact = b1p. One block/net.
__global__ __launch_bounds__(256) void psi0_kernel(
    const float* __restrict__ b1p, const bf16_t* __restrict__ W2t,
    const float* __restrict__ b2, const bf16_t* __restrict__ W3t,
    float* __restrict__ psi0) {
    int j = blockIdx.x, tid = threadIdx.x;
    __shared__ float h1[256], h2[256];
    {
        float v = b1p[j * 256 + tid];
        h1[tid] = fmaxf(v, 0.01f * v);
    }
    __syncthreads();
    {
        float acc = b2[j * 256 + tid];
        const bf16_t* wrow = W2t + (size_t)(j * 256 + tid) * 256;
        for (int d = 0; d < 256; d++) acc += h1[d] * (float)wrow[d];
        h2[tid] = fmaxf(acc, 0.01f * acc);
    }
    __syncthreads();
    if (tid < 128) {
        float acc = 0.f;
        const bf16_t* wrow = W3t + (size_t)(j * 128 + tid) * 256;
        for (int d = 0; d < 256; d++) acc += h2[d] * (float)wrow[d];
        psi0[j * 128 + tid] = acc;
    }
}

// y = (sum_j phi[m][j][:]) @ C^T, phi layout [m][j][128]. Block per (ti, b).
__global__ __launch_bounds__(128) void y_kernel(
    const bf16_t* __restrict__ phi, const float* __restrict__ C_W,
    float* __restrict__ y) {
    int ti = blockIdx.x, b = blockIdx.y, l = threadIdx.x;
    __shared__ float S[128];
    const int m = b * 64 + ti + 1;
    const bf16_t* pp = phi + (size_t)m * 8192 + l;
    float s = 0.f;
    #pragma unroll 8
    for (int j = 0; j < 64; j++) s += (float)pp[j * 128];
    S[l] = s;
    __syncthreads();
    if (l < 16) {
        float acc = 0.f;
        for (int ll = 0; ll < 128; ll++) acc += S[ll] * C_W[l * 128 + ll];
        y[(b * 63 + ti) * 16 + l] = acc;
    }
}

// Koopman scan + j-sum + decode. One block/batch, 4 waves x 16 nets/lane.
// psiu/phi layout [m][j][128] -> per-step working set is 16KB contiguous.
__global__ __launch_bounds__(256) void recur_kernel(
    const bf16_t* __restrict__ phi, const bf16_t* __restrict__ psiu,
    const float* __restrict__ psi0, const float* __restrict__ reL,
    const float* __restrict__ imL, const float* __restrict__ C_W,
    float* __restrict__ ypred) {
    const int b = blockIdx.x;
    const int tid = threadIdx.x;
    const int wave = tid >> 6, lane = tid & 63;
    __shared__ float red[4][128];
    __shared__ float S[128];
    __shared__ float Cs[2048];
    for (int i = tid; i < 2048; i += 256) Cs[i] = C_W[i];

    float sx[16], sy[16], p0x[16], p0y[16], lre[16], lim[16];
    const size_t base_phi = (size_t)b * 64 * 8192;
    #pragma unroll
    for (int i = 0; i < 16; i++) {
        const int j = wave * 16 + i;
        unsigned v = *reinterpret_cast<const unsigned*>(phi + base_phi + j * 128 + lane * 2);
        sx[i] = __uint_as_float(v << 16);
        sy[i] = __uint_as_float(v & 0xFFFF0000u);
        float2 p0 = *reinterpret_cast<const float2*>(psi0 + j * 128 + lane * 2);
        p0x[i] = p0.x; p0y[i] = p0.y;
        lre[i] = reL[j]; lim[i] = imL[j];
    }
    __syncthreads();

    for (int t = 0; t < 63; t++) {
        const bf16_t* up = psiu + (size_t)(b * 63 + t) * 8192 + lane * 2;
        float lsx = 0.f, lsy = 0.f;
        #pragma unroll
        for (int i = 0; i < 16; i++) {
            const int j = wave * 16 + i;
            unsigned v = *reinterpret_cast<const unsigned*>(up + j * 128);
            float px = sx[i] + (__uint_as_float(v << 16) - p0x[i]);
            float py = sy[i] + (__uint_as_float(v & 0xFFFF0000u) - p0y[i]);
            sx[i] = px * lre[i] - py * lim[i];
            sy[i] = px * lim[i] + py * lre[i];
            lsx += sx[i]; lsy += sy[i];
        }
        red[wave][lane * 2]     = lsx;
        red[wave][lane * 2 + 1] = lsy;
        __syncthreads();
        if (tid < 128) S[tid] = red[0][tid] + red[1][tid] + red[2][tid] + red[3][tid];
        __syncthreads();
        if (tid < 128) {
            const int o = tid >> 3, sub = tid & 7;
            float acc = 0.f;
            #pragma unroll
            for (int i = 0; i < 16; i++)
                acc += S[sub * 16 + i] * Cs[o * 128 + sub * 16 + i];
            acc += __shfl_xor(acc, 4, 8);
            acc += __shfl_xor(acc, 2, 8);
            acc += __shfl_xor(acc, 1, 8);
            if (sub == 0) ypred[(b * 63 + t) * 16 + o] = acc;
        }
        __syncthreads();
    }
}

// ---------------------------------------------------------------------------
extern "C" void kernel_launch(void* const* d_in, const int* in_sizes, int n_in,
                              void* d_out, int out_size, void* d_ws, size_t ws_size,
                              hipStream_t stream) {
    const float* xs      = (const float*)d_in[0];
    const float* us      = (const float*)d_in[1];
    const float* x_gamma = (const float*)d_in[2];
    const float* x_beta  = (const float*)d_in[3];
    const float* xW1     = (const float*)d_in[4];
    const float* xb1     = (const float*)d_in[5];
    const float* xW2     = (const float*)d_in[6];
    const float* xb2     = (const float*)d_in[7];
    const float* xW3     = (const float*)d_in[8];
    const float* x_scale = (const float*)d_in[9];
    const float* u_gamma = (const float*)d_in[10];
    const float* u_beta  = (const float*)d_in[11];
    const float* uW1     = (const float*)d_in[12];
    const float* ub1     = (const float*)d_in[13];
    const float* uW2     = (const float*)d_in[14];
    const float* ub2     = (const float*)d_in[15];
    const float* uW3     = (const float*)d_in[16];
    const float* u_scale = (const float*)d_in[17];
    const float* reL     = (const float*)d_in[18];
    const float* imL     = (const float*)d_in[19];
    const float* C_W     = (const float*)d_in[20];

    char* ws = (char*)d_ws;
    size_t off = 0;
    auto alloc = [&](size_t bytes) -> char* {
        char* p = ws + off;
        off += (bytes + 255) & ~(size_t)255;
        return p;
    };
    float*  stats_x = (float*)alloc(64 * 4);
    float*  stats_u = (float*)alloc(64 * 4);
    bf16_t* Xn   = (bf16_t*)alloc((size_t)4096 * 32 * 2);
    bf16_t* Un   = (bf16_t*)alloc((size_t)4032 * 32 * 2);
    bf16_t* xW1t = (bf16_t*)alloc((size_t)64 * 256 * 32 * 2);
    float*  xb1p = (float*) alloc((size_t)64 * 256 * 4);
    bf16_t* xW2t = (bf16_t*)alloc((size_t)64 * 256 * 256 * 2);
    bf16_t* xW3t = (bf16_t*)alloc((size_t)64 * 128 * 256 * 2);
    bf16_t* uW1t = (bf16_t*)alloc((size_t)64 * 256 * 32 * 2);
    float*  ub1p = (float*) alloc((size_t)64 * 256 * 4);
    bf16_t* uW2t = (bf16_t*)alloc((size_t)64 * 256 * 256 * 2);
    bf16_t* uW3t = (bf16_t*)alloc((size_t)64 * 128 * 256 * 2);
    float*  psi0 = (float*) alloc((size_t)64 * 128 * 4);
    bf16_t* phi  = (bf16_t*)alloc((size_t)4096 * 64 * 128 * 2);   // [m][j][128]
    bf16_t* psiu = (bf16_t*)alloc((size_t)4032 * 64 * 128 * 2);   // [m][j][128]

    float* y_out     = (float*)d_out;
    float* ypred_out = y_out + 64 * 63 * 16;

    bn_stats_kernel<<<2, 256, 0, stream>>>(xs, us, stats_x, stats_u);
    normalize_kernel<<<1016, 256, 0, stream>>>(xs, us, stats_x, stats_u, Xn, Un);
    prep_w1_kernel<<<128, 256, 0, stream>>>(xW1, xb1, x_gamma, x_beta,
                                            uW1, ub1, u_gamma, u_beta,
                                            xW1t, xb1p, uW1t, ub1p);
    transpose_all_kernel<<<dim3(8, 8, 256), 256, 0, stream>>>(
        xW2, uW2, xW3, uW3, x_scale, u_scale, xW2t, uW2t, xW3t, uW3t);
    psi0_kernel<<<64, 256, 0, stream>>>(ub1p, uW2t, ub2, uW3t, psi0);
    fused_mlp_kernel<<<dim3(127, 64), 256, 0, stream>>>(
        Xn, Un, xW1t, xb1p, xW2t, xb2, xW3t, uW1t, ub1p, uW2t, ub2, uW3t, phi, psiu);
    y_kernel<<<dim3(63, 64), 128, 0, stream>>>(phi, C_W, y_out);
    recur_kernel<<<64, 256, 0, stream>>>(phi, psiu, psi0, reL, imL, C_W, ypred_out);
}

// Round 3
// 562.352 us; speedup vs baseline: 1.3598x; 1.3598x over previous
//
#include <hip/hip_runtime.h>

typedef __bf16 bf16_t;
typedef __bf16 bf16x8 __attribute__((ext_vector_type(8)));
typedef __bf16 bf16x4 __attribute__((ext_vector_type(4)));
typedef float  f32x4  __attribute__((ext_vector_type(4)));

// ---------------------------------------------------------------------------
// BN stats for both inputs in one launch. stats layout: [mu(D), rstd(D)]
__global__ void bn_stats_kernel(const float* __restrict__ xs, const float* __restrict__ us,
                                float* __restrict__ stats_x, float* __restrict__ stats_u) {
    const float* x; int M, D; float* stats;
    if (blockIdx.x == 0) { x = xs; M = 4096; D = 16; stats = stats_x; }
    else                 { x = us; M = 4032; D = 8;  stats = stats_u; }
    __shared__ float s1[256], s2[256];
    int tid = threadIdx.x;
    float a = 0.f, b = 0.f;
    int N = M * D;
    for (int idx = tid; idx < N; idx += 256) {  // 256 % D == 0 keeps col fixed
        float v = x[idx];
        a += v; b += v * v;
    }
    s1[tid] = a; s2[tid] = b;
    __syncthreads();
    if (tid < D) {
        float sa = 0.f, sb = 0.f;
        for (int k = tid; k < 256; k += D) { sa += s1[k]; sb += s2[k]; }
        float mu  = sa / (float)M;
        float var = sb / (float)M - mu * mu;
        stats[tid]     = mu;
        stats[D + tid] = rsqrtf(var + 1e-5f);
    }
}

// Normalize + K-pad to 32 cols, bf16, both inputs in one launch.
__global__ void normalize_kernel(const float* __restrict__ xs, const float* __restrict__ us,
                                 const float* __restrict__ stats_x, const float* __restrict__ stats_u,
                                 bf16_t* __restrict__ Xn, bf16_t* __restrict__ Un) {
    int bx = blockIdx.x;
    const float* x; const float* stats; bf16_t* outp; int M, D, idx;
    if (bx < 512) { x = xs; stats = stats_x; outp = Xn; M = 4096; D = 16; idx = bx * 256 + threadIdx.x; }
    else          { x = us; stats = stats_u; outp = Un; M = 4032; D = 8;  idx = (bx - 512) * 256 + threadIdx.x; }
    if (idx >= M * 32) return;
    int m = idx >> 5, dp = idx & 31;
    float v = 0.f;
    if (dp < D) v = (x[m * D + dp] - stats[dp]) * stats[D + dp];
    outp[idx] = (bf16_t)v;
}

// Fold gamma into W1 (transposed [j][256][32], K-padded, bf16), beta into b1. Both nets.
__global__ __launch_bounds__(256) void prep_w1_kernel(
    const float* __restrict__ xW1, const float* __restrict__ xb1,
    const float* __restrict__ xg,  const float* __restrict__ xbeta,
    const float* __restrict__ uW1, const float* __restrict__ ub1,
    const float* __restrict__ ug,  const float* __restrict__ ubeta,
    bf16_t* __restrict__ xW1t, float* __restrict__ xb1p,
    bf16_t* __restrict__ uW1t, float* __restrict__ ub1p) {
    int bid = blockIdx.x, j = bid & 63, h = threadIdx.x;
    const float *W1, *b1, *gamma, *beta; bf16_t* W1t; float* b1p; int D;
    if (bid < 64) { W1 = xW1; b1 = xb1; gamma = xg; beta = xbeta; W1t = xW1t; b1p = xb1p; D = 16; }
    else          { W1 = uW1; b1 = ub1; gamma = ug; beta = ubeta; W1t = uW1t; b1p = ub1p; D = 8; }
    float bacc = b1[j * 256 + h];
    bf16_t* orow = W1t + (size_t)(j * 256 + h) * 32;
    for (int d = 0; d < 32; d++) orow[d] = (bf16_t)0.f;
    for (int d = 0; d < D; d++) {
        float w = W1[((size_t)j * D + d) * 256 + h];
        orow[d] = (bf16_t)(gamma[j * D + d] * w);
        bacc += beta[j * D + d] * w;
    }
    b1p[j * 256 + h] = bacc;
}

// All four weight transposes (fp32 [64][256][C] -> bf16 [64][C][256]) in one launch.
__global__ __launch_bounds__(256) void transpose_all_kernel(
    const float* __restrict__ xW2, const float* __restrict__ uW2,
    const float* __restrict__ xW3, const float* __restrict__ uW3,
    const float* __restrict__ x_scale, const float* __restrict__ u_scale,
    bf16_t* __restrict__ xW2t, bf16_t* __restrict__ uW2t,
    bf16_t* __restrict__ xW3t, bf16_t* __restrict__ uW3t) {
    __shared__ float tile[32][33];
    int z = blockIdx.z, b = z & 63;
    const float* in; bf16_t* outp; const float* scale = nullptr; int C;
    if (z < 64)       { in = xW2; outp = xW2t; C = 256; }
    else if (z < 128) { in = uW2; outp = uW2t; C = 256; }
    else if (z < 192) { in = xW3; outp = xW3t; scale = x_scale + b * 128; C = 128; if (blockIdx.x >= 4) return; }
    else              { in = uW3; outp = uW3t; scale = u_scale + b * 128; C = 128; if (blockIdx.x >= 4) return; }
    const int R = 256;
    in   += (size_t)b * R * C;
    outp += (size_t)b * R * C;
    int r0 = blockIdx.y * 32, c0 = blockIdx.x * 32;
    int tx = threadIdx.x & 31, ty = threadIdx.x >> 5;
    #pragma unroll
    for (int i = 0; i < 4; i++)
        tile[ty + i * 8][tx] = in[(size_t)(r0 + ty + i * 8) * C + c0 + tx];
    __syncthreads();
    #pragma unroll
    for (int i = 0; i < 4; i++) {
        int c = c0 + ty + i * 8;
        float sc = scale ? scale[c] : 1.f;
        outp[(size_t)c * R + r0 + tx] = (bf16_t)(tile[tx][ty + i * 8] * sc);
    }
}

// ---------------------------------------------------------------------------
// Fused 3-layer MLP. MFMA operands SWAPPED (A=weights, B=activations) so D has
// row = h (4 consecutive per thread) and col = m -> b64 LDS writes + direct
// global stores. hs layout [m][h] with 16B-slot XOR swizzle (slot ^ (m&15)).
// Output layout [j][m][128] (contiguous 16KB slab per block).
// 1D grid with XCD j-banding: xcd = n&7 owns nets xcd*8..xcd*8+7.
__global__ __launch_bounds__(256, 4) void fused_mlp_kernel(
    const bf16_t* __restrict__ Xn, const bf16_t* __restrict__ Un,
    const bf16_t* __restrict__ xW1t, const float* __restrict__ xb1p,
    const bf16_t* __restrict__ xW2t, const float* __restrict__ xb2,
    const bf16_t* __restrict__ xW3t,
    const bf16_t* __restrict__ uW1t, const float* __restrict__ ub1p,
    const bf16_t* __restrict__ uW2t, const float* __restrict__ ub2,
    const bf16_t* __restrict__ uW3t,
    bf16_t* __restrict__ phi, bf16_t* __restrict__ psiu)
{
    const int n    = blockIdx.x;
    const int xcd  = n & 7;
    const int slot = n >> 3;
    const int band = slot / 127;
    const int t127 = slot - band * 127;
    const int j    = xcd * 8 + band;
    const bool is_x = t127 < 64;
    const int tile  = is_x ? t127 : (t127 - 64);

    const bf16_t* In  = is_x ? Xn   : Un;
    const bf16_t* W1t = is_x ? xW1t : uW1t;
    const float*  b1p = is_x ? xb1p : ub1p;
    const bf16_t* W2t = is_x ? xW2t : uW2t;
    const float*  b2  = is_x ? xb2  : ub2;
    const bf16_t* W3t = is_x ? xW3t : uW3t;
    bf16_t* outp      = is_x ? phi  : psiu;
    const int M       = is_x ? 4096 : 4032;

    const int row0 = tile * 64;
    const int tid  = threadIdx.x;
    const int wave = tid >> 6;
    const int lane = tid & 63;
    const int quad = lane >> 4;
    const int l16  = lane & 15;

    __shared__ __align__(16) bf16_t hs[64 * 256];   // 32 KB, reused h1 -> h2

    const f32x4 vzero = {0.f, 0.f, 0.f, 0.f};

    // ---------------- layer 1 (K=32, zero-padded) ----------------
    {
        bf16x8 act[4];
        #pragma unroll
        for (int mb = 0; mb < 4; mb++)
            act[mb] = *reinterpret_cast<const bf16x8*>(
                In + (size_t)(row0 + mb * 16 + l16) * 32 + quad * 8);

        f32x4 acc[4][4];
        #pragma unroll
        for (int a = 0; a < 4; a++)
            #pragma unroll
            for (int c = 0; c < 4; c++) acc[a][c] = vzero;

        #pragma unroll
        for (int nbi = 0; nbi < 4; nbi++) {
            bf16x8 wfr = *reinterpret_cast<const bf16x8*>(
                W1t + (size_t)(j * 256 + (wave * 4 + nbi) * 16 + l16) * 32 + quad * 8);
            #pragma unroll
            for (int mb = 0; mb < 4; mb++)
                acc[mb][nbi] = __builtin_amdgcn_mfma_f32_16x16x32_bf16(
                    wfr, act[mb], acc[mb][nbi], 0, 0, 0);
        }
        #pragma unroll
        for (int nbi = 0; nbi < 4; nbi++) {
            const f32x4 bias = *reinterpret_cast<const f32x4*>(
                b1p + j * 256 + (wave * 4 + nbi) * 16 + quad * 4);
            const int sl = (wave * 4 + nbi) * 2 + (quad >> 1);
            const int sp = sl ^ l16;
            const int half = quad & 1;
            #pragma unroll
            for (int mb = 0; mb < 4; mb++) {
                const int m = mb * 16 + l16;
                bf16x4 pk;
                #pragma unroll
                for (int r = 0; r < 4; r++) {
                    float v = acc[mb][nbi][r] + bias[r];
                    v = fmaxf(v, 0.01f * v);
                    pk[r] = (bf16_t)v;
                }
                *reinterpret_cast<bf16x4*>(hs + m * 256 + sp * 8 + half * 4) = pk;
            }
        }
    }
    __syncthreads();

    // ---------------- layer 2 (256x256), acc in regs, then overwrite hs ------
    {
        f32x4 acc[4][4];
        #pragma unroll
        for (int a = 0; a < 4; a++)
            #pragma unroll
            for (int c = 0; c < 4; c++) acc[a][c] = vzero;

        #pragma unroll
        for (int kk = 0; kk < 8; kk++) {
            bf16x8 av[4];
            #pragma unroll
            for (int mb = 0; mb < 4; mb++) {
                const int m  = mb * 16 + l16;
                const int sp = (kk * 4 + quad) ^ l16;
                av[mb] = *reinterpret_cast<const bf16x8*>(hs + m * 256 + sp * 8);
            }
            #pragma unroll
            for (int nbi = 0; nbi < 4; nbi++) {
                bf16x8 wfr = *reinterpret_cast<const bf16x8*>(
                    W2t + (size_t)(j * 256 + (wave * 4 + nbi) * 16 + l16) * 256 + kk * 32 + quad * 8);
                #pragma unroll
                for (int mb = 0; mb < 4; mb++)
                    acc[mb][nbi] = __builtin_amdgcn_mfma_f32_16x16x32_bf16(
                        wfr, av[mb], acc[mb][nbi], 0, 0, 0);
            }
        }
        __syncthreads();   // all h1 reads done; safe to overwrite
        #pragma unroll
        for (int nbi = 0; nbi < 4; nbi++) {
            const f32x4 bias = *reinterpret_cast<const f32x4*>(
                b2 + j * 256 + (wave * 4 + nbi) * 16 + quad * 4);
            const int sl = (wave * 4 + nbi) * 2 + (quad >> 1);
            const int sp = sl ^ l16;
            const int half = quad & 1;
            #pragma unroll
            for (int mb = 0; mb < 4; mb++) {
                const int m = mb * 16 + l16;
                bf16x4 pk;
                #pragma unroll
                for (int r = 0; r < 4; r++) {
                    float v = acc[mb][nbi][r] + bias[r];
                    v = fmaxf(v, 0.01f * v);
                    pk[r] = (bf16_t)v;
                }
                *reinterpret_cast<bf16x4*>(hs + m * 256 + sp * 8 + half * 4) = pk;
            }
        }
    }
    __syncthreads();

    // ---------------- layer 3 (256x128, scale folded): direct global store ---
    {
        f32x4 acc[4][2];
        #pragma unroll
        for (int a = 0; a < 4; a++) { acc[a][0] = vzero; acc[a][1] = vzero; }

        #pragma unroll
        for (int kk = 0; kk < 8; kk++) {
            bf16x8 av[4];
            #pragma unroll
            for (int mb = 0; mb < 4; mb++) {
                const int m  = mb * 16 + l16;
                const int sp = (kk * 4 + quad) ^ l16;
                av[mb] = *reinterpret_cast<const bf16x8*>(hs + m * 256 + sp * 8);
            }
            #pragma unroll
            for (int nbi = 0; nbi < 2; nbi++) {
                bf16x8 wfr = *reinterpret_cast<const bf16x8*>(
                    W3t + (size_t)(j * 128 + (wave * 2 + nbi) * 16 + l16) * 256 + kk * 32 + quad * 8);
                #pragma unroll
                for (int mb = 0; mb < 4; mb++)
                    acc[mb][nbi] = __builtin_amdgcn_mfma_f32_16x16x32_bf16(
                        wfr, av[mb], acc[mb][nbi], 0, 0, 0);
            }
        }
        #pragma unroll
        for (int nbi = 0; nbi < 2; nbi++) {
            const int h = (wave * 2 + nbi) * 16 + quad * 4;
            #pragma unroll
            for (int mb = 0; mb < 4; mb++) {
                const int m = mb * 16 + l16;
                bf16x4 pk;
                #pragma unroll
                for (int r = 0; r < 4; r++) pk[r] = (bf16_t)acc[mb][nbi][r];
                *reinterpret_cast<bf16x4*>(
                    outp + ((size_t)j * M + row0 + m) * 128 + h) = pk;
            }
        }
    }
}

// ---------------------------------------------------------------------------
// psi(0) per net: xn=0 -> layer1 preact = b1p. One block/net.
__global__ __launch_bounds__(256) void psi0_kernel(
    const float* __restrict__ b1p, const bf16_t* __restrict__ W2t,
    const float* __restrict__ b2, const bf16_t* __restrict__ W3t,
    float* __restrict__ psi0) {
    int j = blockIdx.x, tid = threadIdx.x;
    __shared__ float h1[256], h2[256];
    {
        float v = b1p[j * 256 + tid];
        h1[tid] = fmaxf(v, 0.01f * v);
    }
    __syncthreads();
    {
        float acc = b2[j * 256 + tid];
        const bf16_t* wrow = W2t + (size_t)(j * 256 + tid) * 256;
        for (int d = 0; d < 256; d++) acc += h1[d] * (float)wrow[d];
        h2[tid] = fmaxf(acc, 0.01f * acc);
    }
    __syncthreads();
    if (tid < 128) {
        float acc = 0.f;
        const bf16_t* wrow = W3t + (size_t)(j * 128 + tid) * 256;
        for (int d = 0; d < 256; d++) acc += h2[d] * (float)wrow[d];
        psi0[j * 128 + tid] = acc;
    }
}

// y = (sum_j phi[j][m][:]) @ C^T, phi layout [j][m][128]. Block per (ti, b).
__global__ __launch_bounds__(128) void y_kernel(
    const bf16_t* __restrict__ phi, const float* __restrict__ C_W,
    float* __restrict__ y) {
    int ti = blockIdx.x, b = blockIdx.y, l = threadIdx.x;
    __shared__ float S[128];
    const int m = b * 64 + ti + 1;
    const bf16_t* pp = phi + (size_t)m * 128 + l;
    float s = 0.f;
    #pragma unroll 8
    for (int j = 0; j < 64; j++) s += (float)pp[(size_t)j * 524288];
    S[l] = s;
    __syncthreads();
    if (l < 16) {
        float acc = 0.f;
        for (int ll = 0; ll < 128; ll++) acc += S[ll] * C_W[l * 128 + ll];
        y[(b * 63 + ti) * 16 + l] = acc;
    }
}

// Koopman scan, split over j: block = (b, jg) handles 8 nets, 4 waves x 2 nets.
// Writes per-group partial sums S_partial[t][128] to scratch (contiguous/block).
__global__ __launch_bounds__(256) void scan_kernel(
    const bf16_t* __restrict__ phi, const bf16_t* __restrict__ psiu,
    const float* __restrict__ psi0, const float* __restrict__ reL,
    const float* __restrict__ imL, float* __restrict__ scratch) {
    const int b = blockIdx.x >> 3, jg = blockIdx.x & 7;
    const int tid = threadIdx.x;
    const int wave = tid >> 6, lane = tid & 63;
    __shared__ float red[2][4][128];

    float sx[2], sy[2], p0x[2], p0y[2], lre[2], lim[2];
    #pragma unroll
    for (int i = 0; i < 2; i++) {
        const int j = jg * 8 + wave * 2 + i;
        unsigned v = *reinterpret_cast<const unsigned*>(
            phi + ((size_t)j * 4096 + b * 64) * 128 + lane * 2);
        sx[i] = __uint_as_float(v << 16);
        sy[i] = __uint_as_float(v & 0xFFFF0000u);
        float2 p0 = *reinterpret_cast<const float2*>(psi0 + j * 128 + lane * 2);
        p0x[i] = p0.x; p0y[i] = p0.y;
        lre[i] = reL[j]; lim[i] = imL[j];
    }
    float* out = scratch + (size_t)blockIdx.x * 63 * 128;

    for (int t = 0; t < 63; t++) {
        float lsx = 0.f, lsy = 0.f;
        #pragma unroll
        for (int i = 0; i < 2; i++) {
            const int j = jg * 8 + wave * 2 + i;
            unsigned v = *reinterpret_cast<const unsigned*>(
                psiu + ((size_t)j * 4032 + b * 63 + t) * 128 + lane * 2);
            float px = sx[i] + (__uint_as_float(v << 16) - p0x[i]);
            float py = sy[i] + (__uint_as_float(v & 0xFFFF0000u) - p0y[i]);
            sx[i] = px * lre[i] - py * lim[i];
            sy[i] = px * lim[i] + py * lre[i];
            lsx += sx[i]; lsy += sy[i];
        }
        const int db = t & 1;
        red[db][wave][lane * 2]     = lsx;
        red[db][wave][lane * 2 + 1] = lsy;
        __syncthreads();
        if (tid < 128)
            out[t * 128 + tid] = red[db][0][tid] + red[db][1][tid]
                               + red[db][2][tid] + red[db][3][tid];
        // next iter writes the other red buffer -> single barrier per t is safe
    }
}

// Sum the 8 j-group partials and decode: ypred[b][t][16]. One wave per (t,b).
__global__ __launch_bounds__(64) void decode_kernel(
    const float* __restrict__ scratch, const float* __restrict__ C_W,
    float* __restrict__ ypred) {
    const int t = blockIdx.x, b = blockIdx.y, l = threadIdx.x;
    __shared__ float S[128];
    float s0 = 0.f, s1 = 0.f;
    #pragma unroll
    for (int jg = 0; jg < 8; jg++) {
        float2 v = *reinterpret_cast<const float2*>(
            scratch + ((size_t)(b * 8 + jg) * 63 + t) * 128 + l * 2);
        s0 += v.x; s1 += v.y;
    }
    S[l * 2] = s0; S[l * 2 + 1] = s1;
    __syncthreads();
    const int o = l >> 2, q = l & 3;
    float acc = 0.f;
    #pragma unroll
    for (int i = 0; i < 32; i++)
        acc += S[q * 32 + i] * C_W[o * 128 + q * 32 + i];
    acc += __shfl_xor(acc, 2, 4);
    acc += __shfl_xor(acc, 1, 4);
    if (q == 0) ypred[(b * 63 + t) * 16 + o] = acc;
}

// ---------------------------------------------------------------------------
extern "C" void kernel_launch(void* const* d_in, const int* in_sizes, int n_in,
                              void* d_out, int out_size, void* d_ws, size_t ws_size,
                              hipStream_t stream) {
    const float* xs      = (const float*)d_in[0];
    const float* us      = (const float*)d_in[1];
    const float* x_gamma = (const float*)d_in[2];
    const float* x_beta  = (const float*)d_in[3];
    const float* xW1     = (const float*)d_in[4];
    const float* xb1     = (const float*)d_in[5];
    const float* xW2     = (const float*)d_in[6];
    const float* xb2     = (const float*)d_in[7];
    const float* xW3     = (const float*)d_in[8];
    const float* x_scale = (const float*)d_in[9];
    const float* u_gamma = (const float*)d_in[10];
    const float* u_beta  = (const float*)d_in[11];
    const float* uW1     = (const float*)d_in[12];
    const float* ub1     = (const float*)d_in[13];
    const float* uW2     = (const float*)d_in[14];
    const float* ub2     = (const float*)d_in[15];
    const float* uW3     = (const float*)d_in[16];
    const float* u_scale = (const float*)d_in[17];
    const float* reL     = (const float*)d_in[18];
    const float* imL     = (const float*)d_in[19];
    const float* C_W     = (const float*)d_in[20];

    char* ws = (char*)d_ws;
    size_t off = 0;
    auto alloc = [&](size_t bytes) -> char* {
        char* p = ws + off;
        off += (bytes + 255) & ~(size_t)255;
        return p;
    };
    float*  stats_x = (float*)alloc(64 * 4);
    float*  stats_u = (float*)alloc(64 * 4);
    bf16_t* Xn   = (bf16_t*)alloc((size_t)4096 * 32 * 2);
    bf16_t* Un   = (bf16_t*)alloc((size_t)4032 * 32 * 2);
    bf16_t* xW1t = (bf16_t*)alloc((size_t)64 * 256 * 32 * 2);
    float*  xb1p = (float*) alloc((size_t)64 * 256 * 4);
    bf16_t* xW2t = (bf16_t*)alloc((size_t)64 * 256 * 256 * 2);
    bf16_t* xW3t = (bf16_t*)alloc((size_t)64 * 128 * 256 * 2);
    bf16_t* uW1t = (bf16_t*)alloc((size_t)64 * 256 * 32 * 2);
    float*  ub1p = (float*) alloc((size_t)64 * 256 * 4);
    bf16_t* uW2t = (bf16_t*)alloc((size_t)64 * 256 * 256 * 2);
    bf16_t* uW3t = (bf16_t*)alloc((size_t)64 * 128 * 256 * 2);
    float*  psi0 = (float*) alloc((size_t)64 * 128 * 4);
    bf16_t* phi  = (bf16_t*)alloc((size_t)64 * 4096 * 128 * 2);   // [j][m][128]
    bf16_t* psiu = (bf16_t*)alloc((size_t)64 * 4032 * 128 * 2);   // [j][m][128]
    float*  scr  = (float*) alloc((size_t)512 * 63 * 128 * 4);    // scan partials

    float* y_out     = (float*)d_out;
    float* ypred_out = y_out + 64 * 63 * 16;

    bn_stats_kernel<<<2, 256, 0, stream>>>(xs, us, stats_x, stats_u);
    normalize_kernel<<<1016, 256, 0, stream>>>(xs, us, stats_x, stats_u, Xn, Un);
    prep_w1_kernel<<<128, 256, 0, stream>>>(xW1, xb1, x_gamma, x_beta,
                                            uW1, ub1, u_gamma, u_beta,
                                            xW1t, xb1p, uW1t, ub1p);
    transpose_all_kernel<<<dim3(8, 8, 256), 256, 0, stream>>>(
        xW2, uW2, xW3, uW3, x_scale, u_scale, xW2t, uW2t, xW3t, uW3t);
    psi0_kernel<<<64, 256, 0, stream>>>(ub1p, uW2t, ub2, uW3t, psi0);
    fused_mlp_kernel<<<8128, 256, 0, stream>>>(
        Xn, Un, xW1t, xb1p, xW2t, xb2, xW3t, uW1t, ub1p, uW2t, ub2, uW3t, phi, psiu);
    y_kernel<<<dim3(63, 64), 128, 0, stream>>>(phi, C_W, y_out);
    scan_kernel<<<512, 256, 0, stream>>>(phi, psiu, psi0, reL, imL, scr);
    decode_kernel<<<dim3(63, 64), 64, 0, stream>>>(scr, C_W, ypred_out);
}

// Round 4
// 526.959 us; speedup vs baseline: 1.4511x; 1.0672x over previous
//
#include <hip/hip_runtime.h>

typedef __bf16 bf16_t;
typedef __bf16 bf16x8 __attribute__((ext_vector_type(8)));
typedef __bf16 bf16x4 __attribute__((ext_vector_type(4)));
typedef float  f32x4  __attribute__((ext_vector_type(4)));

// ---------------------------------------------------------------------------
// BN stats for both inputs in one launch. stats layout: [mu(D), rstd(D)]
__global__ void bn_stats_kernel(const float* __restrict__ xs, const float* __restrict__ us,
                                float* __restrict__ stats_x, float* __restrict__ stats_u) {
    const float* x; int M, D; float* stats;
    if (blockIdx.x == 0) { x = xs; M = 4096; D = 16; stats = stats_x; }
    else                 { x = us; M = 4032; D = 8;  stats = stats_u; }
    __shared__ float s1[256], s2[256];
    int tid = threadIdx.x;
    float a = 0.f, b = 0.f;
    int N = M * D;
    for (int idx = tid; idx < N; idx += 256) {  // 256 % D == 0 keeps col fixed
        float v = x[idx];
        a += v; b += v * v;
    }
    s1[tid] = a; s2[tid] = b;
    __syncthreads();
    if (tid < D) {
        float sa = 0.f, sb = 0.f;
        for (int k = tid; k < 256; k += D) { sa += s1[k]; sb += s2[k]; }
        float mu  = sa / (float)M;
        float var = sb / (float)M - mu * mu;
        stats[tid]     = mu;
        stats[D + tid] = rsqrtf(var + 1e-5f);
    }
}

// Fold gamma into W1 (transposed [j][256][32], K-padded, bf16), beta into b1. Both nets.
__global__ __launch_bounds__(256) void prep_w1_kernel(
    const float* __restrict__ xW1, const float* __restrict__ xb1,
    const float* __restrict__ xg,  const float* __restrict__ xbeta,
    const float* __restrict__ uW1, const float* __restrict__ ub1,
    const float* __restrict__ ug,  const float* __restrict__ ubeta,
    bf16_t* __restrict__ xW1t, float* __restrict__ xb1p,
    bf16_t* __restrict__ uW1t, float* __restrict__ ub1p) {
    int bid = blockIdx.x, j = bid & 63, h = threadIdx.x;
    const float *W1, *b1, *gamma, *beta; bf16_t* W1t; float* b1p; int D;
    if (bid < 64) { W1 = xW1; b1 = xb1; gamma = xg; beta = xbeta; W1t = xW1t; b1p = xb1p; D = 16; }
    else          { W1 = uW1; b1 = ub1; gamma = ug; beta = ubeta; W1t = uW1t; b1p = ub1p; D = 8; }
    float bacc = b1[j * 256 + h];
    bf16_t* orow = W1t + (size_t)(j * 256 + h) * 32;
    for (int d = 0; d < 32; d++) orow[d] = (bf16_t)0.f;
    for (int d = 0; d < D; d++) {
        float w = W1[((size_t)j * D + d) * 256 + h];
        orow[d] = (bf16_t)(gamma[j * D + d] * w);
        bacc += beta[j * D + d] * w;
    }
    b1p[j * 256 + h] = bacc;
}

// All four weight transposes (fp32 [64][256][C] -> bf16 [64][C][256]) in one launch.
__global__ __launch_bounds__(256) void transpose_all_kernel(
    const float* __restrict__ xW2, const float* __restrict__ uW2,
    const float* __restrict__ xW3, const float* __restrict__ uW3,
    const float* __restrict__ x_scale, const float* __restrict__ u_scale,
    bf16_t* __restrict__ xW2t, bf16_t* __restrict__ uW2t,
    bf16_t* __restrict__ xW3t, bf16_t* __restrict__ uW3t) {
    __shared__ float tile[32][33];
    int z = blockIdx.z, b = z & 63;
    const float* in; bf16_t* outp; const float* scale = nullptr; int C;
    if (z < 64)       { in = xW2; outp = xW2t; C = 256; }
    else if (z < 128) { in = uW2; outp = uW2t; C = 256; }
    else if (z < 192) { in = xW3; outp = xW3t; scale = x_scale + b * 128; C = 128; if (blockIdx.x >= 4) return; }
    else              { in = uW3; outp = uW3t; scale = u_scale + b * 128; C = 128; if (blockIdx.x >= 4) return; }
    const int R = 256;
    in   += (size_t)b * R * C;
    outp += (size_t)b * R * C;
    int r0 = blockIdx.y * 32, c0 = blockIdx.x * 32;
    int tx = threadIdx.x & 31, ty = threadIdx.x >> 5;
    #pragma unroll
    for (int i = 0; i < 4; i++)
        tile[ty + i * 8][tx] = in[(size_t)(r0 + ty + i * 8) * C + c0 + tx];
    __syncthreads();
    #pragma unroll
    for (int i = 0; i < 4; i++) {
        int c = c0 + ty + i * 8;
        float sc = scale ? scale[c] : 1.f;
        outp[(size_t)c * R + r0 + tx] = (bf16_t)(tile[tx][ty + i * 8] * sc);
    }
}

// ---------------------------------------------------------------------------
// Fused BN-normalize + 3-layer MLP. A=weights, B=activations (D: row=h, col=m).
// Double-buffered prefetch of weight (global) and activation (LDS) fragments.
// Epilogue stages through LDS for full-line contiguous global stores.
// Output layout [j][m][128]. XCD j-banding: xcd = bid&7 owns nets xcd*8..+7.
__global__ __launch_bounds__(256, 2) void fused_mlp_kernel(
    const float* __restrict__ xs, const float* __restrict__ us,
    const float* __restrict__ stats_x, const float* __restrict__ stats_u,
    const bf16_t* __restrict__ xW1t, const float* __restrict__ xb1p,
    const bf16_t* __restrict__ xW2t, const float* __restrict__ xb2,
    const bf16_t* __restrict__ xW3t,
    const bf16_t* __restrict__ uW1t, const float* __restrict__ ub1p,
    const bf16_t* __restrict__ uW2t, const float* __restrict__ ub2,
    const bf16_t* __restrict__ uW3t,
    bf16_t* __restrict__ phi, bf16_t* __restrict__ psiu)
{
    const int bid  = blockIdx.x;
    const int xcd  = bid & 7;
    const int slot = bid >> 3;
    const int band = slot / 127;
    const int t127 = slot - band * 127;
    const int j    = xcd * 8 + band;
    const bool is_x = t127 < 64;
    const int tile  = is_x ? t127 : (t127 - 64);

    const float*  In    = is_x ? xs      : us;
    const float*  stats = is_x ? stats_x : stats_u;
    const int     D     = is_x ? 16      : 8;
    const bf16_t* W1t = is_x ? xW1t : uW1t;
    const float*  b1p = is_x ? xb1p : ub1p;
    const bf16_t* W2t = is_x ? xW2t : uW2t;
    const float*  b2  = is_x ? xb2  : ub2;
    const bf16_t* W3t = is_x ? xW3t : uW3t;
    bf16_t* outp      = is_x ? phi  : psiu;
    const int M       = is_x ? 4096 : 4032;

    const int row0 = tile * 64;
    const int tid  = threadIdx.x;
    const int wave = tid >> 6;
    const int lane = tid & 63;
    const int quad = lane >> 4;
    const int l16  = lane & 15;

    __shared__ __align__(16) bf16_t hs[64 * 256];   // 32 KB, reused h1 -> h2 -> out

    const f32x4 vzero = {0.f, 0.f, 0.f, 0.f};

    // ---------------- layer 1 (K=32, normalize folded in) ----------------
    {
        // weight frags (issue first, independent)
        bf16x8 wfr[4];
        #pragma unroll
        for (int nbi = 0; nbi < 4; nbi++)
            wfr[nbi] = *reinterpret_cast<const bf16x8*>(
                W1t + (size_t)(j * 256 + (wave * 4 + nbi) * 16 + l16) * 32 + quad * 8);

        // activation frags: B[k=quad*8+e][m=l16], normalize on the fly
        bf16x8 act[4];
        const int c0 = quad * 8;
        if (c0 < D) {
            float mu[8], rs[8];
            #pragma unroll
            for (int e = 0; e < 8; e++) { mu[e] = stats[c0 + e]; rs[e] = stats[D + c0 + e]; }
            #pragma unroll
            for (int mb = 0; mb < 4; mb++) {
                const float* xp = In + (size_t)(row0 + mb * 16 + l16) * D + c0;
                f32x4 v0 = *reinterpret_cast<const f32x4*>(xp);
                f32x4 v1 = *reinterpret_cast<const f32x4*>(xp + 4);
                bf16x8 a;
                #pragma unroll
                for (int e = 0; e < 4; e++) a[e]     = (bf16_t)((v0[e] - mu[e])     * rs[e]);
                #pragma unroll
                for (int e = 0; e < 4; e++) a[4 + e] = (bf16_t)((v1[e] - mu[4 + e]) * rs[4 + e]);
                act[mb] = a;
            }
        } else {
            #pragma unroll
            for (int mb = 0; mb < 4; mb++) {
                bf16x8 a;
                #pragma unroll
                for (int e = 0; e < 8; e++) a[e] = (bf16_t)0.f;
                act[mb] = a;
            }
        }

        f32x4 acc[4][4];
        #pragma unroll
        for (int a = 0; a < 4; a++)
            #pragma unroll
            for (int c = 0; c < 4; c++) acc[a][c] = vzero;

        #pragma unroll
        for (int nbi = 0; nbi < 4; nbi++)
            #pragma unroll
            for (int mb = 0; mb < 4; mb++)
                acc[mb][nbi] = __builtin_amdgcn_mfma_f32_16x16x32_bf16(
                    wfr[nbi], act[mb], acc[mb][nbi], 0, 0, 0);

        #pragma unroll
        for (int nbi = 0; nbi < 4; nbi++) {
            const f32x4 bias = *reinterpret_cast<const f32x4*>(
                b1p + j * 256 + (wave * 4 + nbi) * 16 + quad * 4);
            const int sl = (wave * 4 + nbi) * 2 + (quad >> 1);
            const int half = quad & 1;
            const int sp = sl ^ l16;
            #pragma unroll
            for (int mb = 0; mb < 4; mb++) {
                const int m = mb * 16 + l16;
                bf16x4 pk;
                #pragma unroll
                for (int r = 0; r < 4; r++) {
                    float v = acc[mb][nbi][r] + bias[r];
                    v = fmaxf(v, 0.01f * v);
                    pk[r] = (bf16_t)v;
                }
                *reinterpret_cast<bf16x4*>(hs + m * 256 + sp * 8 + half * 4) = pk;
            }
        }
    }
    __syncthreads();

    // ---------------- layer 2 (256x256), double-buffered prefetch ----------
    {
        f32x4 acc[4][4];
        #pragma unroll
        for (int a = 0; a < 4; a++)
            #pragma unroll
            for (int c = 0; c < 4; c++) acc[a][c] = vzero;

        const bf16_t* w2base = W2t + ((size_t)j * 256 + (wave * 4) * 16 + l16) * 256 + quad * 8;

        bf16x8 wb[2][4], ab[2][4];
        #pragma unroll
        for (int nbi = 0; nbi < 4; nbi++)
            wb[0][nbi] = *reinterpret_cast<const bf16x8*>(w2base + nbi * 4096);
        #pragma unroll
        for (int mb = 0; mb < 4; mb++) {
            const int m = mb * 16 + l16;
            ab[0][mb] = *reinterpret_cast<const bf16x8*>(hs + m * 256 + ((0 + quad) ^ l16) * 8);
        }
        #pragma unroll
        for (int kk = 0; kk < 8; kk++) {
            const int cb = kk & 1, nb = cb ^ 1;
            if (kk < 7) {
                #pragma unroll
                for (int nbi = 0; nbi < 4; nbi++)
                    wb[nb][nbi] = *reinterpret_cast<const bf16x8*>(
                        w2base + nbi * 4096 + (kk + 1) * 32);
                #pragma unroll
                for (int mb = 0; mb < 4; mb++) {
                    const int m = mb * 16 + l16;
                    ab[nb][mb] = *reinterpret_cast<const bf16x8*>(
                        hs + m * 256 + (((kk + 1) * 4 + quad) ^ l16) * 8);
                }
            }
            #pragma unroll
            for (int nbi = 0; nbi < 4; nbi++)
                #pragma unroll
                for (int mb = 0; mb < 4; mb++)
                    acc[mb][nbi] = __builtin_amdgcn_mfma_f32_16x16x32_bf16(
                        wb[cb][nbi], ab[cb][mb], acc[mb][nbi], 0, 0, 0);
        }
        __syncthreads();   // all h1 reads done; safe to overwrite
        #pragma unroll
        for (int nbi = 0; nbi < 4; nbi++) {
            const f32x4 bias = *reinterpret_cast<const f32x4*>(
                b2 + j * 256 + (wave * 4 + nbi) * 16 + quad * 4);
            const int sl = (wave * 4 + nbi) * 2 + (quad >> 1);
            const int half = quad & 1;
            const int sp = sl ^ l16;
            #pragma unroll
            for (int mb = 0; mb < 4; mb++) {
                const int m = mb * 16 + l16;
                bf16x4 pk;
                #pragma unroll
                for (int r = 0; r < 4; r++) {
                    float v = acc[mb][nbi][r] + bias[r];
                    v = fmaxf(v, 0.01f * v);
                    pk[r] = (bf16_t)v;
                }
                *reinterpret_cast<bf16x4*>(hs + m * 256 + sp * 8 + half * 4) = pk;
            }
        }
    }
    __syncthreads();

    // ---------------- layer 3 (256x128), double-buffered prefetch -----------
    {
        f32x4 acc[4][2];
        #pragma unroll
        for (int a = 0; a < 4; a++) { acc[a][0] = vzero; acc[a][1] = vzero; }

        const bf16_t* w3base = W3t + ((size_t)j * 128 + (wave * 2) * 16 + l16) * 256 + quad * 8;

        bf16x8 wb[2][2], ab[2][4];
        #pragma unroll
        for (int nbi = 0; nbi < 2; nbi++)
            wb[0][nbi] = *reinterpret_cast<const bf16x8*>(w3base + nbi * 4096);
        #pragma unroll
        for (int mb = 0; mb < 4; mb++) {
            const int m = mb * 16 + l16;
            ab[0][mb] = *reinterpret_cast<const bf16x8*>(hs + m * 256 + ((0 + quad) ^ l16) * 8);
        }
        #pragma unroll
        for (int kk = 0; kk < 8; kk++) {
            const int cb = kk & 1, nb = cb ^ 1;
            if (kk < 7) {
                #pragma unroll
                for (int nbi = 0; nbi < 2; nbi++)
                    wb[nb][nbi] = *reinterpret_cast<const bf16x8*>(
                        w3base + nbi * 4096 + (kk + 1) * 32);
                #pragma unroll
                for (int mb = 0; mb < 4; mb++) {
                    const int m = mb * 16 + l16;
                    ab[nb][mb] = *reinterpret_cast<const bf16x8*>(
                        hs + m * 256 + (((kk + 1) * 4 + quad) ^ l16) * 8);
                }
            }
            #pragma unroll
            for (int nbi = 0; nbi < 2; nbi++)
                #pragma unroll
                for (int mb = 0; mb < 4; mb++)
                    acc[mb][nbi] = __builtin_amdgcn_mfma_f32_16x16x32_bf16(
                        wb[cb][nbi], ab[cb][mb], acc[mb][nbi], 0, 0, 0);
        }
        __syncthreads();   // all h2 reads done; hs reusable as [64][128] stage
        #pragma unroll
        for (int nbi = 0; nbi < 2; nbi++) {
            const int s = (wave * 2 + nbi) * 2 + (quad >> 1);   // 16B granule of h
            const int half = quad & 1;
            #pragma unroll
            for (int mb = 0; mb < 4; mb++) {
                const int m = mb * 16 + l16;
                const int sp = s ^ l16;
                bf16x4 pk;
                #pragma unroll
                for (int r = 0; r < 4; r++) pk[r] = (bf16_t)acc[mb][nbi][r];
                *reinterpret_cast<bf16x4*>(hs + m * 128 + sp * 8 + half * 4) = pk;
            }
        }
    }
    __syncthreads();
    // contiguous global write: wave w writes rows p*16+(tid>>4), 1KB/wave-instr
    #pragma unroll
    for (int p = 0; p < 4; p++) {
        const int rr = p * 16 + (tid >> 4);
        const int s  = tid & 15;
        const int sp = s ^ (rr & 15);
        bf16x8 v = *reinterpret_cast<const bf16x8*>(hs + rr * 128 + sp * 8);
        *reinterpret_cast<bf16x8*>(outp + ((size_t)j * M + row0 + rr) * 128 + s * 8) = v;
    }
}

// ---------------------------------------------------------------------------
// psi(0) per net: xn=0 -> layer1 preact = b1p. One block/net.
__global__ __launch_bounds__(256) void psi0_kernel(
    const float* __restrict__ b1p, const bf16_t* __restrict__ W2t,
    const float* __restrict__ b2, const bf16_t* __restrict__ W3t,
    float* __restrict__ psi0) {
    int j = blockIdx.x, tid = threadIdx.x;
    __shared__ float h1[256], h2[256];
    {
        float v = b1p[j * 256 + tid];
        h1[tid] = fmaxf(v, 0.01f * v);
    }
    __syncthreads();
    {
        float acc = b2[j * 256 + tid];
        const bf16_t* wrow = W2t + (size_t)(j * 256 + tid) * 256;
        for (int d = 0; d < 256; d++) acc += h1[d] * (float)wrow[d];
        h2[tid] = fmaxf(acc, 0.01f * acc);
    }
    __syncthreads();
    if (tid < 128) {
        float acc = 0.f;
        const bf16_t* wrow = W3t + (size_t)(j * 128 + tid) * 256;
        for (int d = 0; d < 256; d++) acc += h2[d] * (float)wrow[d];
        psi0[j * 128 + tid] = acc;
    }
}

// y = (sum_j phi[j][m][:]) @ C^T. Block per 32-row m-tile; coalesced j-loop.
__global__ __launch_bounds__(256) void y_kernel(
    const bf16_t* __restrict__ phi, const float* __restrict__ C_W,
    float* __restrict__ y) {
    const int m0 = blockIdx.x * 32;
    const int tid = threadIdx.x;
    const int r  = tid >> 3;            // 0..31 row within tile
    const int cg = (tid & 7) * 16;      // 16-col group
    float acc[16];
    #pragma unroll
    for (int e = 0; e < 16; e++) acc[e] = 0.f;
    const bf16_t* p = phi + (size_t)(m0 + r) * 128 + cg;
    for (int j = 0; j < 64; j++) {
        bf16x8 v0 = *reinterpret_cast<const bf16x8*>(p + (size_t)j * 524288);
        bf16x8 v1 = *reinterpret_cast<const bf16x8*>(p + (size_t)j * 524288 + 8);
        #pragma unroll
        for (int e = 0; e < 8; e++) { acc[e] += (float)v0[e]; acc[8 + e] += (float)v1[e]; }
    }
    __shared__ float S[32][128];
    #pragma unroll
    for (int e = 0; e < 16; e++) S[r][cg + e] = acc[e];
    __syncthreads();
    #pragma unroll
    for (int i = 0; i < 2; i++) {
        const int idx = tid + i * 256;          // 0..511
        const int mm = idx >> 4, o = idx & 15;
        const int m = m0 + mm;
        if ((m & 63) != 0) {
            float a = 0.f;
            for (int l = 0; l < 128; l++) a += S[mm][l] * C_W[o * 128 + l];
            const int b = m >> 6, ti = (m & 63) - 1;
            y[(b * 63 + ti) * 16 + o] = a;
        }
    }
}

// Koopman scan, split over j: block = (b, jg) handles 8 nets, 4 waves x 2 nets.
__global__ __launch_bounds__(256) void scan_kernel(
    const bf16_t* __restrict__ phi, const bf16_t* __restrict__ psiu,
    const float* __restrict__ psi0, const float* __restrict__ reL,
    const float* __restrict__ imL, float* __restrict__ scratch) {
    const int b = blockIdx.x >> 3, jg = blockIdx.x & 7;
    const int tid = threadIdx.x;
    const int wave = tid >> 6, lane = tid & 63;
    __shared__ float red[2][4][128];

    float sx[2], sy[2], p0x[2], p0y[2], lre[2], lim[2];
    #pragma unroll
    for (int i = 0; i < 2; i++) {
        const int j = jg * 8 + wave * 2 + i;
        unsigned v = *reinterpret_cast<const unsigned*>(
            phi + ((size_t)j * 4096 + b * 64) * 128 + lane * 2);
        sx[i] = __uint_as_float(v << 16);
        sy[i] = __uint_as_float(v & 0xFFFF0000u);
        float2 p0 = *reinterpret_cast<const float2*>(psi0 + j * 128 + lane * 2);
        p0x[i] = p0.x; p0y[i] = p0.y;
        lre[i] = reL[j]; lim[i] = imL[j];
    }
    float* out = scratch + (size_t)blockIdx.x * 63 * 128;

    for (int t = 0; t < 63; t++) {
        float lsx = 0.f, lsy = 0.f;
        #pragma unroll
        for (int i = 0; i < 2; i++) {
            const int j = jg * 8 + wave * 2 + i;
            unsigned v = *reinterpret_cast<const unsigned*>(
                psiu + ((size_t)j * 4032 + b * 63 + t) * 128 + lane * 2);
            float px = sx[i] + (__uint_as_float(v << 16) - p0x[i]);
            float py = sy[i] + (__uint_as_float(v & 0xFFFF0000u) - p0y[i]);
            sx[i] = px * lre[i] - py * lim[i];
            sy[i] = px * lim[i] + py * lre[i];
            lsx += sx[i]; lsy += sy[i];
        }
        const int db = t & 1;
        red[db][wave][lane * 2]     = lsx;
        red[db][wave][lane * 2 + 1] = lsy;
        __syncthreads();
        if (tid < 128)
            out[t * 128 + tid] = red[db][0][tid] + red[db][1][tid]
                               + red[db][2][tid] + red[db][3][tid];
        // next iter writes the other red buffer -> single barrier per t is safe
    }
}

// Sum the 8 j-group partials and decode: ypred[b][t][16]. One wave per (t,b).
__global__ __launch_bounds__(64) void decode_kernel(
    const float* __restrict__ scratch, const float* __restrict__ C_W,
    float* __restrict__ ypred) {
    const int t = blockIdx.x, b = blockIdx.y, l = threadIdx.x;
    __shared__ float S[128];
    float s0 = 0.f, s1 = 0.f;
    #pragma unroll
    for (int jg = 0; jg < 8; jg++) {
        float2 v = *reinterpret_cast<const float2*>(
            scratch + ((size_t)(b * 8 + jg) * 63 + t) * 128 + l * 2);
        s0 += v.x; s1 += v.y;
    }
    S[l * 2] = s0; S[l * 2 + 1] = s1;
    __syncthreads();
    const int o = l >> 2, q = l & 3;
    float acc = 0.f;
    #pragma unroll
    for (int i = 0; i < 32; i++)
        acc += S[q * 32 + i] * C_W[o * 128 + q * 32 + i];
    acc += __shfl_xor(acc, 2, 4);
    acc += __shfl_xor(acc, 1, 4);
    if (q == 0) ypred[(b * 63 + t) * 16 + o] = acc;
}

// ---------------------------------------------------------------------------
extern "C" void kernel_launch(void* const* d_in, const int* in_sizes, int n_in,
                              void* d_out, int out_size, void* d_ws, size_t ws_size,
                              hipStream_t stream) {
    const float* xs      = (const float*)d_in[0];
    const float* us      = (const float*)d_in[1];
    const float* x_gamma = (const float*)d_in[2];
    const float* x_beta  = (const float*)d_in[3];
    const float* xW1     = (const float*)d_in[4];
    const float* xb1     = (const float*)d_in[5];
    const float* xW2     = (const float*)d_in[6];
    const float* xb2     = (const float*)d_in[7];
    const float* xW3     = (const float*)d_in[8];
    const float* x_scale = (const float*)d_in[9];
    const float* u_gamma = (const float*)d_in[10];
    const float* u_beta  = (const float*)d_in[11];
    const float* uW1     = (const float*)d_in[12];
    const float* ub1     = (const float*)d_in[13];
    const float* uW2     = (const float*)d_in[14];
    const float* ub2     = (const float*)d_in[15];
    const float* uW3     = (const float*)d_in[16];
    const float* u_scale = (const float*)d_in[17];
    const float* reL     = (const float*)d_in[18];
    const float* imL     = (const float*)d_in[19];
    const float* C_W     = (const float*)d_in[20];

    char* ws = (char*)d_ws;
    size_t off = 0;
    auto alloc = [&](size_t bytes) -> char* {
        char* p = ws + off;
        off += (bytes + 255) & ~(size_t)255;
        return p;
    };
    float*  stats_x = (float*)alloc(64 * 4);
    float*  stats_u = (float*)alloc(64 * 4);
    bf16_t* xW1t = (bf16_t*)alloc((size_t)64 * 256 * 32 * 2);
    float*  xb1p = (float*) alloc((size_t)64 * 256 * 4);
    bf16_t* xW2t = (bf16_t*)alloc((size_t)64 * 256 * 256 * 2);
    bf16_t* xW3t = (bf16_t*)alloc((size_t)64 * 128 * 256 * 2);
    bf16_t* uW1t = (bf16_t*)alloc((size_t)64 * 256 * 32 * 2);
    float*  ub1p = (float*) alloc((size_t)64 * 256 * 4);
    bf16_t* uW2t = (bf16_t*)alloc((size_t)64 * 256 * 256 * 2);
    bf16_t* uW3t = (bf16_t*)alloc((size_t)64 * 128 * 256 * 2);
    float*  psi0 = (float*) alloc((size_t)64 * 128 * 4);
    bf16_t* phi  = (bf16_t*)alloc((size_t)64 * 4096 * 128 * 2);   // [j][m][128]
    bf16_t* psiu = (bf16_t*)alloc((size_t)64 * 4032 * 128 * 2);   // [j][m][128]
    float*  scr  = (float*) alloc((size_t)512 * 63 * 128 * 4);    // scan partials

    float* y_out     = (float*)d_out;
    float* ypred_out = y_out + 64 * 63 * 16;

    bn_stats_kernel<<<2, 256, 0, stream>>>(xs, us, stats_x, stats_u);
    prep_w1_kernel<<<128, 256, 0, stream>>>(xW1, xb1, x_gamma, x_beta,
                                            uW1, ub1, u_gamma, u_beta,
                                            xW1t, xb1p, uW1t, ub1p);
    transpose_all_kernel<<<dim3(8, 8, 256), 256, 0, stream>>>(
        xW2, uW2, xW3, uW3, x_scale, u_scale, xW2t, uW2t, xW3t, uW3t);
    psi0_kernel<<<64, 256, 0, stream>>>(ub1p, uW2t, ub2, uW3t, psi0);
    fused_mlp_kernel<<<8128, 256, 0, stream>>>(
        xs, us, stats_x, stats_u,
        xW1t, xb1p, xW2t, xb2, xW3t, uW1t, ub1p, uW2t, ub2, uW3t, phi, psiu);
    y_kernel<<<128, 256, 0, stream>>>(phi, C_W, y_out);
    scan_kernel<<<512, 256, 0, stream>>>(phi, psiu, psi0, reL, imL, scr);
    decode_kernel<<<dim3(63, 64), 64, 0, stream>>>(scr, C_W, ypred_out);
}

// Round 5
// 380.272 us; speedup vs baseline: 2.0108x; 1.3857x over previous
//
#include <hip/hip_runtime.h>

typedef __bf16 bf16_t;
typedef __bf16 bf16x8 __attribute__((ext_vector_type(8)));
typedef __bf16 bf16x4 __attribute__((ext_vector_type(4)));
typedef float  f32x4  __attribute__((ext_vector_type(4)));

// ---------------------------------------------------------------------------
// BN stats stage 1: 96 blocks of per-feature partial sums (blocks 0..63 x, 64..95 u).
// part[bid][0][d] = sum, part[bid][1][d] = sumsq  (stride 32 floats per block)
__global__ __launch_bounds__(256) void bn_partial_kernel(
    const float* __restrict__ xs, const float* __restrict__ us,
    float* __restrict__ part) {
    const int bid = blockIdx.x, tid = threadIdx.x;
    const bool isx = bid < 64;
    const float* x = isx ? xs : us;
    const int D   = isx ? 16 : 8;
    const int lb  = isx ? bid : bid - 64;
    const int per = isx ? (4096 * 16 / 64) : (4032 * 8 / 32);  // 1024 / 1008 (both % D == 0)
    const int start = lb * per;
    float a = 0.f, b = 0.f;
    for (int idx = start + tid; idx < start + per; idx += 256) {  // 256 % D == 0
        float v = x[idx];
        a += v; b += v * v;
    }
    __shared__ float s1[256], s2[256];
    s1[tid] = a; s2[tid] = b;
    __syncthreads();
    if (tid < D) {
        float sa = 0.f, sb = 0.f;
        for (int k = tid; k < 256; k += D) { sa += s1[k]; sb += s2[k]; }
        part[bid * 32 + tid]      = sa;
        part[bid * 32 + 16 + tid] = sb;
    }
}

// BN stats stage 2: reduce partials -> stats [mu(D), rstd(D)]
__global__ __launch_bounds__(64) void bn_final_kernel(
    const float* __restrict__ part, float* __restrict__ stats_x, float* __restrict__ stats_u) {
    const int tid = threadIdx.x;
    if (tid < 16) {
        float sa = 0.f, sb = 0.f;
        for (int b = 0; b < 64; b++) { sa += part[b * 32 + tid]; sb += part[b * 32 + 16 + tid]; }
        float mu = sa / 4096.f, var = sb / 4096.f - mu * mu;
        stats_x[tid] = mu; stats_x[16 + tid] = rsqrtf(var + 1e-5f);
    } else if (tid >= 32 && tid < 40) {
        const int d = tid - 32;
        float sa = 0.f, sb = 0.f;
        for (int b = 64; b < 96; b++) { sa += part[b * 32 + d]; sb += part[b * 32 + 16 + d]; }
        float mu = sa / 4032.f, var = sb / 4032.f - mu * mu;
        stats_u[d] = mu; stats_u[8 + d] = rsqrtf(var + 1e-5f);
    }
}

// Fold gamma into W1 (transposed [j][256][32], K-padded, bf16), beta into b1. Both nets.
__global__ __launch_bounds__(256) void prep_w1_kernel(
    const float* __restrict__ xW1, const float* __restrict__ xb1,
    const float* __restrict__ xg,  const float* __restrict__ xbeta,
    const float* __restrict__ uW1, const float* __restrict__ ub1,
    const float* __restrict__ ug,  const float* __restrict__ ubeta,
    bf16_t* __restrict__ xW1t, float* __restrict__ xb1p,
    bf16_t* __restrict__ uW1t, float* __restrict__ ub1p) {
    int bid = blockIdx.x, j = bid & 63, h = threadIdx.x;
    const float *W1, *b1, *gamma, *beta; bf16_t* W1t; float* b1p; int D;
    if (bid < 64) { W1 = xW1; b1 = xb1; gamma = xg; beta = xbeta; W1t = xW1t; b1p = xb1p; D = 16; }
    else          { W1 = uW1; b1 = ub1; gamma = ug; beta = ubeta; W1t = uW1t; b1p = ub1p; D = 8; }
    float bacc = b1[j * 256 + h];
    bf16_t* orow = W1t + (size_t)(j * 256 + h) * 32;
    for (int d = 0; d < 32; d++) orow[d] = (bf16_t)0.f;
    for (int d = 0; d < D; d++) {
        float w = W1[((size_t)j * D + d) * 256 + h];
        orow[d] = (bf16_t)(gamma[j * D + d] * w);
        bacc += beta[j * D + d] * w;
    }
    b1p[j * 256 + h] = bacc;
}

// All four weight transposes (fp32 [64][256][C] -> bf16 [64][C][256]) in one launch.
__global__ __launch_bounds__(256) void transpose_all_kernel(
    const float* __restrict__ xW2, const float* __restrict__ uW2,
    const float* __restrict__ xW3, const float* __restrict__ uW3,
    const float* __restrict__ x_scale, const float* __restrict__ u_scale,
    bf16_t* __restrict__ xW2t, bf16_t* __restrict__ uW2t,
    bf16_t* __restrict__ xW3t, bf16_t* __restrict__ uW3t) {
    __shared__ float tile[32][33];
    int z = blockIdx.z, b = z & 63;
    const float* in; bf16_t* outp; const float* scale = nullptr; int C;
    if (z < 64)       { in = xW2; outp = xW2t; C = 256; }
    else if (z < 128) { in = uW2; outp = uW2t; C = 256; }
    else if (z < 192) { in = xW3; outp = xW3t; scale = x_scale + b * 128; C = 128; if (blockIdx.x >= 4) return; }
    else              { in = uW3; outp = uW3t; scale = u_scale + b * 128; C = 128; if (blockIdx.x >= 4) return; }
    const int R = 256;
    in   += (size_t)b * R * C;
    outp += (size_t)b * R * C;
    int r0 = blockIdx.y * 32, c0 = blockIdx.x * 32;
    int tx = threadIdx.x & 31, ty = threadIdx.x >> 5;
    #pragma unroll
    for (int i = 0; i < 4; i++)
        tile[ty + i * 8][tx] = in[(size_t)(r0 + ty + i * 8) * C + c0 + tx];
    __syncthreads();
    #pragma unroll
    for (int i = 0; i < 4; i++) {
        int c = c0 + ty + i * 8;
        float sc = scale ? scale[c] : 1.f;
        outp[(size_t)c * R + r0 + tx] = (bf16_t)(tile[tx][ty + i * 8] * sc);
    }
}

// ---------------------------------------------------------------------------
// Fused BN-normalize + 3-layer MLP. 512 threads (8 waves), m-tile = 128 rows,
// wave w owns n-slice w*32 (layer1/2) and w*16 (layer3). A=weights,
// B=activations. Depth-3 weight prefetch ring hides L2 latency. LDS 64KB
// (h-tile), 2 blocks/CU; __launch_bounds__(512,4) caps regs at 128/wave.
// Output [j][m][128]. XCD j-banding: xcd = bid&7 owns nets xcd*8..+7.
__global__ __launch_bounds__(512, 4) void fused_mlp_kernel(
    const float* __restrict__ xs, const float* __restrict__ us,
    const float* __restrict__ stats_x, const float* __restrict__ stats_u,
    const bf16_t* __restrict__ xW1t, const float* __restrict__ xb1p,
    const bf16_t* __restrict__ xW2t, const float* __restrict__ xb2,
    const bf16_t* __restrict__ xW3t,
    const bf16_t* __restrict__ uW1t, const float* __restrict__ ub1p,
    const bf16_t* __restrict__ uW2t, const float* __restrict__ ub2,
    const bf16_t* __restrict__ uW3t,
    bf16_t* __restrict__ phi, bf16_t* __restrict__ psiu)
{
    const int bid  = blockIdx.x;
    const int xcd  = bid & 7;
    const int slot = bid >> 3;          // 0..511
    const int band = slot >> 6;         // 0..7
    const int t64  = slot & 63;
    const int j    = xcd * 8 + band;
    const bool is_x = t64 < 32;
    const int tile  = is_x ? t64 : (t64 - 32);

    const float*  In    = is_x ? xs      : us;
    const float*  stats = is_x ? stats_x : stats_u;
    const int     D     = is_x ? 16      : 8;
    const bf16_t* W1t = is_x ? xW1t : uW1t;
    const float*  b1p = is_x ? xb1p : ub1p;
    const bf16_t* W2t = is_x ? xW2t : uW2t;
    const float*  b2  = is_x ? xb2  : ub2;
    const bf16_t* W3t = is_x ? xW3t : uW3t;
    bf16_t* outp      = is_x ? phi  : psiu;
    const int M       = is_x ? 4096 : 4032;

    const int row0 = tile * 128;
    const int tid  = threadIdx.x;
    const int wave = tid >> 6;          // 0..7
    const int lane = tid & 63;
    const int quad = lane >> 4;
    const int l16  = lane & 15;

    __shared__ __align__(16) bf16_t hs[128 * 256];   // 64 KB, reused h1 -> h2 -> out

    const f32x4 vzero = {0.f, 0.f, 0.f, 0.f};

    // ---------------- layer 1 (K=32, normalize folded in) ----------------
    {
        // weight frags first (independent)
        bf16x8 wfr[2];
        #pragma unroll
        for (int nbi = 0; nbi < 2; nbi++)
            wfr[nbi] = *reinterpret_cast<const bf16x8*>(
                W1t + (size_t)(j * 256 + wave * 32 + nbi * 16 + l16) * 32 + quad * 8);

        f32x4 acc[8][2];
        #pragma unroll
        for (int a = 0; a < 8; a++) { acc[a][0] = vzero; acc[a][1] = vzero; }

        // activation frags: B[k=quad*8+e][m], normalize on the fly
        const int c0 = quad * 8;
        #pragma unroll
        for (int mb = 0; mb < 8; mb++) {
            bf16x8 a;
            if (c0 < D) {
                int row = row0 + mb * 16 + l16;
                if (row > M - 1) row = M - 1;             // u last tile guard
                const float* xp = In + (size_t)row * D + c0;
                f32x4 v0 = *reinterpret_cast<const f32x4*>(xp);
                f32x4 v1 = *reinterpret_cast<const f32x4*>(xp + 4);
                #pragma unroll
                for (int e = 0; e < 4; e++) a[e]     = (bf16_t)((v0[e] - stats[c0 + e])     * stats[D + c0 + e]);
                #pragma unroll
                for (int e = 0; e < 4; e++) a[4 + e] = (bf16_t)((v1[e] - stats[c0 + 4 + e]) * stats[D + c0 + 4 + e]);
            } else {
                #pragma unroll
                for (int e = 0; e < 8; e++) a[e] = (bf16_t)0.f;
            }
            #pragma unroll
            for (int nbi = 0; nbi < 2; nbi++)
                acc[mb][nbi] = __builtin_amdgcn_mfma_f32_16x16x32_bf16(
                    wfr[nbi], a, acc[mb][nbi], 0, 0, 0);
        }

        #pragma unroll
        for (int nbi = 0; nbi < 2; nbi++) {
            const f32x4 bias = *reinterpret_cast<const f32x4*>(
                b1p + j * 256 + wave * 32 + nbi * 16 + quad * 4);
            const int sl = wave * 4 + nbi * 2 + (quad >> 1);   // h granule 0..31
            const int half = quad & 1;
            const int sp = sl ^ l16;
            #pragma unroll
            for (int mb = 0; mb < 8; mb++) {
                const int m = mb * 16 + l16;
                bf16x4 pk;
                #pragma unroll
                for (int r = 0; r < 4; r++) {
                    float v = acc[mb][nbi][r] + bias[r];
                    v = fmaxf(v, 0.01f * v);
                    pk[r] = (bf16_t)v;
                }
                *reinterpret_cast<bf16x4*>(hs + m * 256 + sp * 8 + half * 4) = pk;
            }
        }
    }
    __syncthreads();

    // ---------------- layer 2 (256x256), depth-3 weight prefetch ring -------
    {
        f32x4 acc[8][2];
        #pragma unroll
        for (int a = 0; a < 8; a++) { acc[a][0] = vzero; acc[a][1] = vzero; }

        const bf16_t* w2base = W2t + ((size_t)j * 256 + wave * 32 + l16) * 256 + quad * 8;

        bf16x8 wr[3][2];
        #pragma unroll
        for (int d = 0; d < 3; d++)
            #pragma unroll
            for (int nbi = 0; nbi < 2; nbi++)
                wr[d][nbi] = *reinterpret_cast<const bf16x8*>(w2base + nbi * 4096 + d * 32);

        #pragma unroll
        for (int kk = 0; kk < 8; kk++) {
            const int c = kk % 3;
            bf16x8 av0[4];
            #pragma unroll
            for (int mb = 0; mb < 4; mb++)
                av0[mb] = *reinterpret_cast<const bf16x8*>(
                    hs + (mb * 16 + l16) * 256 + (((kk * 4 + quad) ^ l16)) * 8);
            #pragma unroll
            for (int nbi = 0; nbi < 2; nbi++)
                #pragma unroll
                for (int mb = 0; mb < 4; mb++)
                    acc[mb][nbi] = __builtin_amdgcn_mfma_f32_16x16x32_bf16(
                        wr[c][nbi], av0[mb], acc[mb][nbi], 0, 0, 0);
            bf16x8 av1[4];
            #pragma unroll
            for (int mb = 4; mb < 8; mb++)
                av1[mb - 4] = *reinterpret_cast<const bf16x8*>(
                    hs + (mb * 16 + l16) * 256 + (((kk * 4 + quad) ^ l16)) * 8);
            #pragma unroll
            for (int nbi = 0; nbi < 2; nbi++)
                #pragma unroll
                for (int mb = 4; mb < 8; mb++)
                    acc[mb][nbi] = __builtin_amdgcn_mfma_f32_16x16x32_bf16(
                        wr[c][nbi], av1[mb - 4], acc[mb][nbi], 0, 0, 0);
            if (kk < 5) {
                #pragma unroll
                for (int nbi = 0; nbi < 2; nbi++)
                    wr[c][nbi] = *reinterpret_cast<const bf16x8*>(
                        w2base + nbi * 4096 + (kk + 3) * 32);
            }
        }
        __syncthreads();   // all h1 reads done; safe to overwrite
        #pragma unroll
        for (int nbi = 0; nbi < 2; nbi++) {
            const f32x4 bias = *reinterpret_cast<const f32x4*>(
                b2 + j * 256 + wave * 32 + nbi * 16 + quad * 4);
            const int sl = wave * 4 + nbi * 2 + (quad >> 1);
            const int half = quad & 1;
            const int sp = sl ^ l16;
            #pragma unroll
            for (int mb = 0; mb < 8; mb++) {
                const int m = mb * 16 + l16;
                bf16x4 pk;
                #pragma unroll
                for (int r = 0; r < 4; r++) {
                    float v = acc[mb][nbi][r] + bias[r];
                    v = fmaxf(v, 0.01f * v);
                    pk[r] = (bf16_t)v;
                }
                *reinterpret_cast<bf16x4*>(hs + m * 256 + sp * 8 + half * 4) = pk;
            }
        }
    }
    __syncthreads();

    // ---------------- layer 3 (256x128), depth-3 weight prefetch ring -------
    {
        f32x4 acc[8];
        #pragma unroll
        for (int a = 0; a < 8; a++) acc[a] = vzero;

        const bf16_t* w3base = W3t + ((size_t)j * 128 + wave * 16 + l16) * 256 + quad * 8;

        bf16x8 wr[3];
        #pragma unroll
        for (int d = 0; d < 3; d++)
            wr[d] = *reinterpret_cast<const bf16x8*>(w3base + d * 32);

        #pragma unroll
        for (int kk = 0; kk < 8; kk++) {
            const int c = kk % 3;
            bf16x8 av0[4];
            #pragma unroll
            for (int mb = 0; mb < 4; mb++)
                av0[mb] = *reinterpret_cast<const bf16x8*>(
                    hs + (mb * 16 + l16) * 256 + (((kk * 4 + quad) ^ l16)) * 8);
            #pragma unroll
            for (int mb = 0; mb < 4; mb++)
                acc[mb] = __builtin_amdgcn_mfma_f32_16x16x32_bf16(
                    wr[c], av0[mb], acc[mb], 0, 0, 0);
            bf16x8 av1[4];
            #pragma unroll
            for (int mb = 4; mb < 8; mb++)
                av1[mb - 4] = *reinterpret_cast<const bf16x8*>(
                    hs + (mb * 16 + l16) * 256 + (((kk * 4 + quad) ^ l16)) * 8);
            #pragma unroll
            for (int mb = 4; mb < 8; mb++)
                acc[mb] = __builtin_amdgcn_mfma_f32_16x16x32_bf16(
                    wr[c], av1[mb - 4], acc[mb], 0, 0, 0);
            if (kk < 5)
                wr[c] = *reinterpret_cast<const bf16x8*>(w3base + (kk + 3) * 32);
        }
        __syncthreads();   // all h2 reads done; hs front 32KB reusable as [128][128]
        {
            const int sl3 = wave * 2 + (quad >> 1);   // h granule 0..15
            const int half = quad & 1;
            #pragma unroll
            for (int mb = 0; mb < 8; mb++) {
                const int m = mb * 16 + l16;
                const int sp = sl3 ^ l16;
                bf16x4 pk;
                #pragma unroll
                for (int r = 0; r < 4; r++) pk[r] = (bf16_t)acc[mb][r];
                *reinterpret_cast<bf16x4*>(hs + m * 128 + sp * 8 + half * 4) = pk;
            }
        }
    }
    __syncthreads();
    // contiguous global write: 4 iterations x 512 threads x 16B = full 32KB slab
    #pragma unroll
    for (int p = 0; p < 4; p++) {
        const int rr = p * 32 + (tid >> 4);
        const int s  = tid & 15;
        if (row0 + rr < M) {
            bf16x8 v = *reinterpret_cast<const bf16x8*>(hs + rr * 128 + (s ^ (rr & 15)) * 8);
            *reinterpret_cast<bf16x8*>(outp + ((size_t)j * M + row0 + rr) * 128 + s * 8) = v;
        }
    }
}

// ---------------------------------------------------------------------------
// psi(0) per net: xn=0 -> layer1 preact = b1p. One block/net.
__global__ __launch_bounds__(256) void psi0_kernel(
    const float* __restrict__ b1p, const bf16_t* __restrict__ W2t,
    const float* __restrict__ b2, const bf16_t* __restrict__ W3t,
    float* __restrict__ psi0) {
    int j = blockIdx.x, tid = threadIdx.x;
    __shared__ float h1[256], h2[256];
    {
        float v = b1p[j * 256 + tid];
        h1[tid] = fmaxf(v, 0.01f * v);
    }
    __syncthreads();
    {
        float acc = b2[j * 256 + tid];
        const bf16_t* wrow = W2t + (size_t)(j * 256 + tid) * 256;
        for (int d = 0; d < 256; d++) acc += h1[d] * (float)wrow[d];
        h2[tid] = fmaxf(acc, 0.01f * acc);
    }
    __syncthreads();
    if (tid < 128) {
        float acc = 0.f;
        const bf16_t* wrow = W3t + (size_t)(j * 128 + tid) * 256;
        for (int d = 0; d < 256; d++) acc += h2[d] * (float)wrow[d];
        psi0[j * 128 + tid] = acc;
    }
}

// y = (sum_j phi[j][m][:]) @ C^T. Block per 32-row m-tile; coalesced j-loop.
__global__ __launch_bounds__(256) void y_kernel(
    const bf16_t* __restrict__ phi, const float* __restrict__ C_W,
    float* __restrict__ y) {
    const int m0 = blockIdx.x * 32;
    const int tid = threadIdx.x;
    const int r  = tid >> 3;            // 0..31 row within tile
    const int cg = (tid & 7) * 16;      // 16-col group
    float acc[16];
    #pragma unroll
    for (int e = 0; e < 16; e++) acc[e] = 0.f;
    const bf16_t* p = phi + (size_t)(m0 + r) * 128 + cg;
    for (int j = 0; j < 64; j++) {
        bf16x8 v0 = *reinterpret_cast<const bf16x8*>(p + (size_t)j * 524288);
        bf16x8 v1 = *reinterpret_cast<const bf16x8*>(p + (size_t)j * 524288 + 8);
        #pragma unroll
        for (int e = 0; e < 8; e++) { acc[e] += (float)v0[e]; acc[8 + e] += (float)v1[e]; }
    }
    __shared__ float S[32][128];
    #pragma unroll
    for (int e = 0; e < 16; e++) S[r][cg + e] = acc[e];
    __syncthreads();
    #pragma unroll
    for (int i = 0; i < 2; i++) {
        const int idx = tid + i * 256;          // 0..511
        const int mm = idx >> 4, o = idx & 15;
        const int m = m0 + mm;
        if ((m & 63) != 0) {
            float a = 0.f;
            for (int l = 0; l < 128; l++) a += S[mm][l] * C_W[o * 128 + l];
            const int b = m >> 6, ti = (m & 63) - 1;
            y[(b * 63 + ti) * 16 + o] = a;
        }
    }
}

// Koopman scan, split over j: block = (b, jg) handles 8 nets, 4 waves x 2 nets.
__global__ __launch_bounds__(256) void scan_kernel(
    const bf16_t* __restrict__ phi, const bf16_t* __restrict__ psiu,
    const float* __restrict__ psi0, const float* __restrict__ reL,
    const float* __restrict__ imL, float* __restrict__ scratch) {
    const int b = blockIdx.x >> 3, jg = blockIdx.x & 7;
    const int tid = threadIdx.x;
    const int wave = tid >> 6, lane = tid & 63;
    __shared__ float red[2][4][128];

    float sx[2], sy[2], p0x[2], p0y[2], lre[2], lim[2];
    #pragma unroll
    for (int i = 0; i < 2; i++) {
        const int j = jg * 8 + wave * 2 + i;
        unsigned v = *reinterpret_cast<const unsigned*>(
            phi + ((size_t)j * 4096 + b * 64) * 128 + lane * 2);
        sx[i] = __uint_as_float(v << 16);
        sy[i] = __uint_as_float(v & 0xFFFF0000u);
        float2 p0 = *reinterpret_cast<const float2*>(psi0 + j * 128 + lane * 2);
        p0x[i] = p0.x; p0y[i] = p0.y;
        lre[i] = reL[j]; lim[i] = imL[j];
    }
    float* out = scratch + (size_t)blockIdx.x * 63 * 128;

    for (int t = 0; t < 63; t++) {
        float lsx = 0.f, lsy = 0.f;
        #pragma unroll
        for (int i = 0; i < 2; i++) {
            const int j = jg * 8 + wave * 2 + i;
            unsigned v = *reinterpret_cast<const unsigned*>(
                psiu + ((size_t)j * 4032 + b * 63 + t) * 128 + lane * 2);
            float px = sx[i] + (__uint_as_float(v << 16) - p0x[i]);
            float py = sy[i] + (__uint_as_float(v & 0xFFFF0000u) - p0y[i]);
            sx[i] = px * lre[i] - py * lim[i];
            sy[i] = px * lim[i] + py * lre[i];
            lsx += sx[i]; lsy += sy[i];
        }
        const int db = t & 1;
        red[db][wave][lane * 2]     = lsx;
        red[db][wave][lane * 2 + 1] = lsy;
        __syncthreads();
        if (tid < 128)
            out[t * 128 + tid] = red[db][0][tid] + red[db][1][tid]
                               + red[db][2][tid] + red[db][3][tid];
        // next iter writes the other red buffer -> single barrier per t is safe
    }
}

// Sum the 8 j-group partials and decode: ypred[b][t][16]. One wave per (t,b).
__global__ __launch_bounds__(64) void decode_kernel(
    const float* __restrict__ scratch, const float* __restrict__ C_W,
    float* __restrict__ ypred) {
    const int t = blockIdx.x, b = blockIdx.y, l = threadIdx.x;
    __shared__ float S[128];
    float s0 = 0.f, s1 = 0.f;
    #pragma unroll
    for (int jg = 0; jg < 8; jg++) {
        float2 v = *reinterpret_cast<const float2*>(
            scratch + ((size_t)(b * 8 + jg) * 63 + t) * 128 + l * 2);
        s0 += v.x; s1 += v.y;
    }
    S[l * 2] = s0; S[l * 2 + 1] = s1;
    __syncthreads();
    const int o = l >> 2, q = l & 3;
    float acc = 0.f;
    #pragma unroll
    for (int i = 0; i < 32; i++)
        acc += S[q * 32 + i] * C_W[o * 128 + q * 32 + i];
    acc += __shfl_xor(acc, 2, 4);
    acc += __shfl_xor(acc, 1, 4);
    if (q == 0) ypred[(b * 63 + t) * 16 + o] = acc;
}

// ---------------------------------------------------------------------------
extern "C" void kernel_launch(void* const* d_in, const int* in_sizes, int n_in,
                              void* d_out, int out_size, void* d_ws, size_t ws_size,
                              hipStream_t stream) {
    const float* xs      = (const float*)d_in[0];
    const float* us      = (const float*)d_in[1];
    const float* x_gamma = (const float*)d_in[2];
    const float* x_beta  = (const float*)d_in[3];
    const float* xW1     = (const float*)d_in[4];
    const float* xb1     = (const float*)d_in[5];
    const float* xW2     = (const float*)d_in[6];
    const float* xb2     = (const float*)d_in[7];
    const float* xW3     = (const float*)d_in[8];
    const float* x_scale = (const float*)d_in[9];
    const float* u_gamma = (const float*)d_in[10];
    const float* u_beta  = (const float*)d_in[11];
    const float* uW1     = (const float*)d_in[12];
    const float* ub1     = (const float*)d_in[13];
    const float* uW2     = (const float*)d_in[14];
    const float* ub2     = (const float*)d_in[15];
    const float* uW3     = (const float*)d_in[16];
    const float* u_scale = (const float*)d_in[17];
    const float* reL     = (const float*)d_in[18];
    const float* imL     = (const float*)d_in[19];
    const float* C_W     = (const float*)d_in[20];

    char* ws = (char*)d_ws;
    size_t off = 0;
    auto alloc = [&](size_t bytes) -> char* {
        char* p = ws + off;
        off += (bytes + 255) & ~(size_t)255;
        return p;
    };
    float*  part    = (float*)alloc(96 * 32 * 4);
    float*  stats_x = (float*)alloc(64 * 4);
    float*  stats_u = (float*)alloc(64 * 4);
    bf16_t* xW1t = (bf16_t*)alloc((size_t)64 * 256 * 32 * 2);
    float*  xb1p = (float*) alloc((size_t)64 * 256 * 4);
    bf16_t* xW2t = (bf16_t*)alloc((size_t)64 * 256 * 256 * 2);
    bf16_t* xW3t = (bf16_t*)alloc((size_t)64 * 128 * 256 * 2);
    bf16_t* uW1t = (bf16_t*)alloc((size_t)64 * 256 * 32 * 2);
    float*  ub1p = (float*) alloc((size_t)64 * 256 * 4);
    bf16_t* uW2t = (bf16_t*)alloc((size_t)64 * 256 * 256 * 2);
    bf16_t* uW3t = (bf16_t*)alloc((size_t)64 * 128 * 256 * 2);
    float*  psi0 = (float*) alloc((size_t)64 * 128 * 4);
    bf16_t* phi  = (bf16_t*)alloc((size_t)64 * 4096 * 128 * 2);   // [j][m][128]
    bf16_t* psiu = (bf16_t*)alloc((size_t)64 * 4032 * 128 * 2);   // [j][m][128]
    float*  scr  = (float*) alloc((size_t)512 * 63 * 128 * 4);    // scan partials

    float* y_out     = (float*)d_out;
    float* ypred_out = y_out + 64 * 63 * 16;

    bn_partial_kernel<<<96, 256, 0, stream>>>(xs, us, part);
    bn_final_kernel<<<1, 64, 0, stream>>>(part, stats_x, stats_u);
    prep_w1_kernel<<<128, 256, 0, stream>>>(xW1, xb1, x_gamma, x_beta,
                                            uW1, ub1, u_gamma, u_beta,
                                            xW1t, xb1p, uW1t, ub1p);
    transpose_all_kernel<<<dim3(8, 8, 256), 256, 0, stream>>>(
        xW2, uW2, xW3, uW3, x_scale, u_scale, xW2t, uW2t, xW3t, uW3t);
    psi0_kernel<<<64, 256, 0, stream>>>(ub1p, uW2t, ub2, uW3t, psi0);
    fused_mlp_kernel<<<4096, 512, 0, stream>>>(
        xs, us, stats_x, stats_u,
        xW1t, xb1p, xW2t, xb2, xW3t, uW1t, ub1p, uW2t, ub2, uW3t, phi, psiu);
    y_kernel<<<128, 256, 0, stream>>>(phi, C_W, y_out);
    scan_kernel<<<512, 256, 0, stream>>>(phi, psiu, psi0, reL, imL, scr);
    decode_kernel<<<dim3(63, 64), 64, 0, stream>>>(scr, C_W, ypred_out);
}

// Round 6
// 361.478 us; speedup vs baseline: 2.1154x; 1.0520x over previous
//
#include <hip/hip_runtime.h>

typedef __bf16 bf16_t;
typedef __bf16 bf16x8 __attribute__((ext_vector_type(8)));
typedef __bf16 bf16x4 __attribute__((ext_vector_type(4)));
typedef float  f32x4  __attribute__((ext_vector_type(4)));

// ---------------------------------------------------------------------------
// ONE preprocessing launch, independent blocks:
//   [0,4096)      xW2 transpose  (fp32 [j][256][256] -> bf16 [j][256][256]^T)
//   [4096,8192)   uW2 transpose
//   [8192,10240)  xW3 transpose + x_scale fold
//   [10240,12288) uW3 transpose + u_scale fold
//   [12288,12416) prep_w1 (gamma fold, transpose, K-pad; beta fold into b1)
//   [12416,12480) psi0 (from RAW u weights; computes ub1p inline)
//   [12480,12576) bn_partial (per-feature sum/sumsq partials)
__global__ __launch_bounds__(256) void prep_all_kernel(
    const float* __restrict__ xW1, const float* __restrict__ xb1,
    const float* __restrict__ xg,  const float* __restrict__ xbeta,
    const float* __restrict__ uW1, const float* __restrict__ ub1,
    const float* __restrict__ ug,  const float* __restrict__ ubeta,
    const float* __restrict__ xW2, const float* __restrict__ uW2,
    const float* __restrict__ xW3, const float* __restrict__ uW3,
    const float* __restrict__ x_scale, const float* __restrict__ u_scale,
    const float* __restrict__ ub2,
    const float* __restrict__ xs, const float* __restrict__ us,
    bf16_t* __restrict__ xW1t, float* __restrict__ xb1p,
    bf16_t* __restrict__ uW1t, float* __restrict__ ub1p,
    bf16_t* __restrict__ xW2t, bf16_t* __restrict__ uW2t,
    bf16_t* __restrict__ xW3t, bf16_t* __restrict__ uW3t,
    float* __restrict__ psi0, float* __restrict__ part)
{
    const int t = blockIdx.x, tid = threadIdx.x;
    __shared__ float tile[32][33];
    __shared__ float h1[256], h2[256];

    if (t < 12288) {
        // ---- weight transposes ----
        const float* in; bf16_t* outp; const float* scale = nullptr;
        int j, r0, c0, C;
        if (t < 8192) {
            C = 256;
            j = (t & 4095) >> 6;
            const int tl = t & 63; r0 = (tl >> 3) * 32; c0 = (tl & 7) * 32;
            if (t < 4096) { in = xW2; outp = xW2t; }
            else          { in = uW2; outp = uW2t; }
        } else {
            C = 128;
            const int l = t - 8192;
            j = (l & 2047) >> 5;
            const int tl = l & 31; r0 = (tl >> 2) * 32; c0 = (tl & 3) * 32;
            if (l < 2048) { in = xW3; outp = xW3t; scale = x_scale + j * 128; }
            else          { in = uW3; outp = uW3t; scale = u_scale + j * 128; }
        }
        const int R = 256;
        in   += (size_t)j * R * C;
        bf16_t* op = outp + (size_t)j * R * C;
        const int tx = tid & 31, ty = tid >> 5;
        #pragma unroll
        for (int i = 0; i < 4; i++)
            tile[ty + i * 8][tx] = in[(size_t)(r0 + ty + i * 8) * C + c0 + tx];
        __syncthreads();
        #pragma unroll
        for (int i = 0; i < 4; i++) {
            int c = c0 + ty + i * 8;
            float sc = scale ? scale[c] : 1.f;
            op[(size_t)c * R + r0 + tx] = (bf16_t)(tile[tx][ty + i * 8] * sc);
        }
    } else if (t < 12416) {
        // ---- prep_w1 ----
        const int bid = t - 12288, j = bid & 63, h = tid;
        const float *W1, *b1, *gamma, *beta; bf16_t* W1t; float* b1p; int D;
        if (bid < 64) { W1 = xW1; b1 = xb1; gamma = xg; beta = xbeta; W1t = xW1t; b1p = xb1p; D = 16; }
        else          { W1 = uW1; b1 = ub1; gamma = ug; beta = ubeta; W1t = uW1t; b1p = ub1p; D = 8; }
        float bacc = b1[j * 256 + h];
        bf16_t* orow = W1t + (size_t)(j * 256 + h) * 32;
        for (int d = 0; d < 32; d++) orow[d] = (bf16_t)0.f;
        for (int d = 0; d < D; d++) {
            float w = W1[((size_t)j * D + d) * 256 + h];
            orow[d] = (bf16_t)(gamma[j * D + d] * w);
            bacc += beta[j * D + d] * w;
        }
        b1p[j * 256 + h] = bacc;
    } else if (t < 12480) {
        // ---- psi0 from raw u weights (no deps on other blocks) ----
        const int j = t - 12416, h = tid;
        {
            float bacc = ub1[j * 256 + h];
            #pragma unroll
            for (int d = 0; d < 8; d++)
                bacc += ubeta[j * 8 + d] * uW1[((size_t)j * 8 + d) * 256 + h];
            h1[h] = fmaxf(bacc, 0.01f * bacc);
        }
        __syncthreads();
        {
            float acc = ub2[j * 256 + h];
            const float* w2 = uW2 + (size_t)j * 65536 + h;
            #pragma unroll 8
            for (int d = 0; d < 256; d++) acc += h1[d] * w2[d * 256];
            h2[h] = fmaxf(acc, 0.01f * acc);
        }
        __syncthreads();
        if (h < 128) {
            float acc = 0.f;
            const float* w3 = uW3 + (size_t)j * 32768 + h;
            #pragma unroll 8
            for (int d = 0; d < 256; d++) acc += h2[d] * w3[d * 128];
            psi0[j * 128 + h] = acc * u_scale[j * 128 + h];
        }
    } else {
        // ---- bn_partial ----
        const int bid = t - 12480;
        const bool isx = bid < 64;
        const float* x = isx ? xs : us;
        const int D   = isx ? 16 : 8;
        const int lb  = isx ? bid : bid - 64;
        const int per = isx ? 1024 : 1008;
        const int start = lb * per;
        float a = 0.f, b = 0.f;
        for (int idx = start + tid; idx < start + per; idx += 256) {
            float v = x[idx];
            a += v; b += v * v;
        }
        float* s1 = h1; float* s2 = h2;
        s1[tid] = a; s2[tid] = b;
        __syncthreads();
        if (tid < D) {
            float sa = 0.f, sb = 0.f;
            for (int k = tid; k < 256; k += D) { sa += s1[k]; sb += s2[k]; }
            part[bid * 32 + tid]      = sa;
            part[bid * 32 + 16 + tid] = sb;
        }
    }
}

// ---------------------------------------------------------------------------
// Fused BN + 3-layer MLP. 512 threads, m-tile 128, A=weights B=activations.
// BN-final inlined (reads `part`). Swizzle decomposed into per-thread
// constants + one xor per kk; mb strides are immediate offsets.
// Output [j][m][128]. XCD j-banding: xcd = bid&7 owns nets xcd*8..+7.
__global__ __launch_bounds__(512, 4) void fused_mlp_kernel(
    const float* __restrict__ xs, const float* __restrict__ us,
    const float* __restrict__ part,
    const bf16_t* __restrict__ xW1t, const float* __restrict__ xb1p,
    const bf16_t* __restrict__ xW2t, const float* __restrict__ xb2,
    const bf16_t* __restrict__ xW3t,
    const bf16_t* __restrict__ uW1t, const float* __restrict__ ub1p,
    const bf16_t* __restrict__ uW2t, const float* __restrict__ ub2,
    const bf16_t* __restrict__ uW3t,
    bf16_t* __restrict__ phi, bf16_t* __restrict__ psiu)
{
    const int bid  = blockIdx.x;
    const int xcd  = bid & 7;
    const int slot = bid >> 3;          // 0..511
    const int band = slot >> 6;         // 0..7
    const int t64  = slot & 63;
    const int j    = xcd * 8 + band;
    const bool is_x = t64 < 32;
    const int tile  = is_x ? t64 : (t64 - 32);

    const float*  In  = is_x ? xs   : us;
    const int     D   = is_x ? 16   : 8;
    const bf16_t* W1t = is_x ? xW1t : uW1t;
    const float*  b1p = is_x ? xb1p : ub1p;
    const bf16_t* W2t = is_x ? xW2t : uW2t;
    const float*  b2  = is_x ? xb2  : ub2;
    const bf16_t* W3t = is_x ? xW3t : uW3t;
    bf16_t* outp      = is_x ? phi  : psiu;
    const int M       = is_x ? 4096 : 4032;

    const int row0 = tile * 128;
    const int tid  = threadIdx.x;
    const int wave = tid >> 6;          // 0..7
    const int lane = tid & 63;
    const int quad = lane >> 4;
    const int l16  = lane & 15;
    const int lo2  = l16 & 3, hi2 = l16 >> 2;

    __shared__ __align__(16) bf16_t hs[128 * 256];   // 64 KB, reused
    __shared__ float stats_s[32];                    // [mu(16), rstd(16)]

    // ---- inline BN final ----
    if (tid < 16) {
        if (is_x) {
            float sa = 0.f, sb = 0.f;
            #pragma unroll 8
            for (int b = 0; b < 64; b++) { sa += part[b * 32 + tid]; sb += part[b * 32 + 16 + tid]; }
            float mu = sa / 4096.f, var = sb / 4096.f - mu * mu;
            stats_s[tid] = mu; stats_s[16 + tid] = rsqrtf(var + 1e-5f);
        } else if (tid < 8) {
            float sa = 0.f, sb = 0.f;
            #pragma unroll 8
            for (int b = 64; b < 96; b++) { sa += part[b * 32 + tid]; sb += part[b * 32 + 16 + tid]; }
            float mu = sa / 4032.f, var = sb / 4032.f - mu * mu;
            stats_s[tid] = mu; stats_s[16 + tid] = rsqrtf(var + 1e-5f);
        }
    }
    __syncthreads();

    const f32x4 vzero = {0.f, 0.f, 0.f, 0.f};

    // per-thread swizzle constants (bytes)
    char* const hsB = (char*)hs;
    const char* const abase = hsB + l16 * 512 + ((quad ^ lo2) << 4);   // A-frag reads
    const int  wlow0 = (quad >> 1) ^ lo2;
    char* const wbase = hsB + l16 * 512 + ((wave ^ hi2) << 6) + ((quad & 1) << 3);

    // ---------------- layer 1 (K=32, BN folded in) ----------------
    {
        bf16x8 wfr[2];
        #pragma unroll
        for (int nbi = 0; nbi < 2; nbi++)
            wfr[nbi] = *reinterpret_cast<const bf16x8*>(
                W1t + (size_t)(j * 256 + wave * 32 + nbi * 16 + l16) * 32 + quad * 8);

        f32x4 acc[8][2];
        #pragma unroll
        for (int a = 0; a < 8; a++) { acc[a][0] = vzero; acc[a][1] = vzero; }

        const int c0 = quad * 8;
        #pragma unroll
        for (int mb = 0; mb < 8; mb++) {
            bf16x8 a;
            if (c0 < D) {
                int row = row0 + mb * 16 + l16;
                if (row > M - 1) row = M - 1;
                const float* xp = In + (size_t)row * D + c0;
                f32x4 v0 = *reinterpret_cast<const f32x4*>(xp);
                f32x4 v1 = *reinterpret_cast<const f32x4*>(xp + 4);
                #pragma unroll
                for (int e = 0; e < 4; e++) a[e]     = (bf16_t)((v0[e] - stats_s[c0 + e])     * stats_s[16 + c0 + e]);
                #pragma unroll
                for (int e = 0; e < 4; e++) a[4 + e] = (bf16_t)((v1[e] - stats_s[c0 + 4 + e]) * stats_s[16 + c0 + 4 + e]);
            } else {
                #pragma unroll
                for (int e = 0; e < 8; e++) a[e] = (bf16_t)0.f;
            }
            #pragma unroll
            for (int nbi = 0; nbi < 2; nbi++)
                acc[mb][nbi] = __builtin_amdgcn_mfma_f32_16x16x32_bf16(
                    wfr[nbi], a, acc[mb][nbi], 0, 0, 0);
        }

        #pragma unroll
        for (int nbi = 0; nbi < 2; nbi++) {
            const f32x4 bias = *reinterpret_cast<const f32x4*>(
                b1p + j * 256 + wave * 32 + nbi * 16 + quad * 4);
            char* wp = wbase + ((wlow0 ^ (nbi << 1)) << 4);
            #pragma unroll
            for (int mb = 0; mb < 8; mb++) {
                bf16x4 pk;
                #pragma unroll
                for (int r = 0; r < 4; r++) {
                    float v = acc[mb][nbi][r] + bias[r];
                    v = fmaxf(v, 0.01f * v);
                    pk[r] = (bf16_t)v;
                }
                *reinterpret_cast<bf16x4*>(wp + mb * 8192) = pk;
            }
        }
    }
    __syncthreads();

    // ---------------- layer 2 (256x256), depth-3 weight ring ----------------
    {
        f32x4 acc[8][2];
        #pragma unroll
        for (int a = 0; a < 8; a++) { acc[a][0] = vzero; acc[a][1] = vzero; }

        const bf16_t* w2base = W2t + ((size_t)j * 256 + wave * 32 + l16) * 256 + quad * 8;

        bf16x8 wr[3][2];
        #pragma unroll
        for (int d = 0; d < 3; d++)
            #pragma unroll
            for (int nbi = 0; nbi < 2; nbi++)
                wr[d][nbi] = *reinterpret_cast<const bf16x8*>(w2base + nbi * 4096 + d * 32);

        #pragma unroll
        for (int kk = 0; kk < 8; kk++) {
            const int c = kk % 3;
            const char* ap = abase + ((kk ^ hi2) << 6);
            bf16x8 av0[4];
            #pragma unroll
            for (int mb = 0; mb < 4; mb++)
                av0[mb] = *reinterpret_cast<const bf16x8*>(ap + mb * 8192);
            #pragma unroll
            for (int nbi = 0; nbi < 2; nbi++)
                #pragma unroll
                for (int mb = 0; mb < 4; mb++)
                    acc[mb][nbi] = __builtin_amdgcn_mfma_f32_16x16x32_bf16(
                        wr[c][nbi], av0[mb], acc[mb][nbi], 0, 0, 0);
            bf16x8 av1[4];
            #pragma unroll
            for (int mb = 0; mb < 4; mb++)
                av1[mb] = *reinterpret_cast<const bf16x8*>(ap + (mb + 4) * 8192);
            #pragma unroll
            for (int nbi = 0; nbi < 2; nbi++)
                #pragma unroll
                for (int mb = 4; mb < 8; mb++)
                    acc[mb][nbi] = __builtin_amdgcn_mfma_f32_16x16x32_bf16(
                        wr[c][nbi], av1[mb - 4], acc[mb][nbi], 0, 0, 0);
            if (kk < 5) {
                #pragma unroll
                for (int nbi = 0; nbi < 2; nbi++)
                    wr[c][nbi] = *reinterpret_cast<const bf16x8*>(
                        w2base + nbi * 4096 + (kk + 3) * 32);
            }
        }
        __syncthreads();
        #pragma unroll
        for (int nbi = 0; nbi < 2; nbi++) {
            const f32x4 bias = *reinterpret_cast<const f32x4*>(
                b2 + j * 256 + wave * 32 + nbi * 16 + quad * 4);
            char* wp = wbase + ((wlow0 ^ (nbi << 1)) << 4);
            #pragma unroll
            for (int mb = 0; mb < 8; mb++) {
                bf16x4 pk;
                #pragma unroll
                for (int r = 0; r < 4; r++) {
                    float v = acc[mb][nbi][r] + bias[r];
                    v = fmaxf(v, 0.01f * v);
                    pk[r] = (bf16_t)v;
                }
                *reinterpret_cast<bf16x4*>(wp + mb * 8192) = pk;
            }
        }
    }
    __syncthreads();

    // ---------------- layer 3 (256x128), depth-3 weight ring ----------------
    {
        f32x4 acc[8];
        #pragma unroll
        for (int a = 0; a < 8; a++) acc[a] = vzero;

        const bf16_t* w3base = W3t + ((size_t)j * 128 + wave * 16 + l16) * 256 + quad * 8;

        bf16x8 wr[3];
        #pragma unroll
        for (int d = 0; d < 3; d++)
            wr[d] = *reinterpret_cast<const bf16x8*>(w3base + d * 32);

        #pragma unroll
        for (int kk = 0; kk < 8; kk++) {
            const int c = kk % 3;
            const char* ap = abase + ((kk ^ hi2) << 6);
            bf16x8 av0[4];
            #pragma unroll
            for (int mb = 0; mb < 4; mb++)
                av0[mb] = *reinterpret_cast<const bf16x8*>(ap + mb * 8192);
            #pragma unroll
            for (int mb = 0; mb < 4; mb++)
                acc[mb] = __builtin_amdgcn_mfma_f32_16x16x32_bf16(
                    wr[c], av0[mb], acc[mb], 0, 0, 0);
            bf16x8 av1[4];
            #pragma unroll
            for (int mb = 0; mb < 4; mb++)
                av1[mb] = *reinterpret_cast<const bf16x8*>(ap + (mb + 4) * 8192);
            #pragma unroll
            for (int mb = 4; mb < 8; mb++)
                acc[mb] = __builtin_amdgcn_mfma_f32_16x16x32_bf16(
                    wr[c], av1[mb - 4], acc[mb], 0, 0, 0);
            if (kk < 5)
                wr[c] = *reinterpret_cast<const bf16x8*>(w3base + (kk + 3) * 32);
        }
        __syncthreads();   // hs reusable as [128][128]
        {
            const int sp3 = (wave * 2 + (quad >> 1)) ^ l16;
            char* w3p = hsB + l16 * 256 + sp3 * 16 + ((quad & 1) << 3);
            #pragma unroll
            for (int mb = 0; mb < 8; mb++) {
                bf16x4 pk;
                #pragma unroll
                for (int r = 0; r < 4; r++) pk[r] = (bf16_t)acc[mb][r];
                *reinterpret_cast<bf16x4*>(w3p + mb * 4096) = pk;
            }
        }
    }
    __syncthreads();
    #pragma unroll
    for (int p = 0; p < 4; p++) {
        const int rr = p * 32 + (tid >> 4);
        const int s  = tid & 15;
        if (row0 + rr < M) {
            bf16x8 v = *reinterpret_cast<const bf16x8*>(hs + rr * 128 + (s ^ (rr & 15)) * 8);
            *reinterpret_cast<bf16x8*>(outp + ((size_t)j * M + row0 + rr) * 128 + s * 8) = v;
        }
    }
}

// ---------------------------------------------------------------------------
// y = (sum_j phi[j][m][:]) @ C^T. 256 blocks x 16-row tiles.
__global__ __launch_bounds__(256) void y_kernel(
    const bf16_t* __restrict__ phi, const float* __restrict__ C_W,
    float* __restrict__ y) {
    const int m0 = blockIdx.x * 16;
    const int tid = threadIdx.x;
    __shared__ float S[16][128];
    __shared__ float Cs[2048];
    #pragma unroll
    for (int i = 0; i < 8; i++) Cs[tid + i * 256] = C_W[tid + i * 256];
    const int r  = tid >> 4;            // 0..15
    const int cg = (tid & 15) * 8;      // 8-col group
    float acc[8];
    #pragma unroll
    for (int e = 0; e < 8; e++) acc[e] = 0.f;
    const bf16_t* p = phi + (size_t)(m0 + r) * 128 + cg;
    for (int j = 0; j < 64; j++) {
        bf16x8 v = *reinterpret_cast<const bf16x8*>(p + (size_t)j * 524288);
        #pragma unroll
        for (int e = 0; e < 8; e++) acc[e] += (float)v[e];
    }
    #pragma unroll
    for (int e = 0; e < 8; e++) S[r][cg + e] = acc[e];
    __syncthreads();
    const int mm = tid >> 4, o = tid & 15;
    const int m = m0 + mm;
    if ((m & 63) != 0) {
        float a = 0.f;
        #pragma unroll 8
        for (int l = 0; l < 128; l++) a += S[mm][l] * Cs[o * 128 + l];
        const int b = m >> 6, ti = (m & 63) - 1;
        y[(b * 63 + ti) * 16 + o] = a;
    }
}

// Koopman scan, split over j: block = (b, jg) handles 8 nets, 4 waves x 2 nets.
// Prefetches t+1's psiu before t's reduce to hide load latency.
__global__ __launch_bounds__(256) void scan_kernel(
    const bf16_t* __restrict__ phi, const bf16_t* __restrict__ psiu,
    const float* __restrict__ psi0, const float* __restrict__ reL,
    const float* __restrict__ imL, float* __restrict__ scratch) {
    const int b = blockIdx.x >> 3, jg = blockIdx.x & 7;
    const int tid = threadIdx.x;
    const int wave = tid >> 6, lane = tid & 63;
    __shared__ float red[2][4][128];

    const int j0 = jg * 8 + wave * 2;
    float sx0, sy0, sx1, sy1;
    float p0x0, p0y0, p0x1, p0y1, lre0, lim0, lre1, lim1;
    {
        unsigned v0 = *reinterpret_cast<const unsigned*>(
            phi + ((size_t)j0 * 4096 + b * 64) * 128 + lane * 2);
        unsigned v1 = *reinterpret_cast<const unsigned*>(
            phi + ((size_t)(j0 + 1) * 4096 + b * 64) * 128 + lane * 2);
        sx0 = __uint_as_float(v0 << 16); sy0 = __uint_as_float(v0 & 0xFFFF0000u);
        sx1 = __uint_as_float(v1 << 16); sy1 = __uint_as_float(v1 & 0xFFFF0000u);
        float2 p0 = *reinterpret_cast<const float2*>(psi0 + j0 * 128 + lane * 2);
        float2 p1 = *reinterpret_cast<const float2*>(psi0 + (j0 + 1) * 128 + lane * 2);
        p0x0 = p0.x; p0y0 = p0.y; p0x1 = p1.x; p0y1 = p1.y;
        lre0 = reL[j0]; lim0 = imL[j0]; lre1 = reL[j0 + 1]; lim1 = imL[j0 + 1];
    }
    const bf16_t* up0 = psiu + ((size_t)j0 * 4032 + b * 63) * 128 + lane * 2;
    const bf16_t* up1 = psiu + ((size_t)(j0 + 1) * 4032 + b * 63) * 128 + lane * 2;
    unsigned cur0 = *reinterpret_cast<const unsigned*>(up0);
    unsigned cur1 = *reinterpret_cast<const unsigned*>(up1);
    float* out = scratch + (size_t)blockIdx.x * 63 * 128;

    for (int t = 0; t < 63; t++) {
        unsigned nx0 = 0, nx1 = 0;
        if (t < 62) {
            nx0 = *reinterpret_cast<const unsigned*>(up0 + (t + 1) * 128);
            nx1 = *reinterpret_cast<const unsigned*>(up1 + (t + 1) * 128);
        }
        float px = sx0 + (__uint_as_float(cur0 << 16) - p0x0);
        float py = sy0 + (__uint_as_float(cur0 & 0xFFFF0000u) - p0y0);
        sx0 = px * lre0 - py * lim0;
        sy0 = px * lim0 + py * lre0;
        px = sx1 + (__uint_as_float(cur1 << 16) - p0x1);
        py = sy1 + (__uint_as_float(cur1 & 0xFFFF0000u) - p0y1);
        sx1 = px * lre1 - py * lim1;
        sy1 = px * lim1 + py * lre1;
        const int db = t & 1;
        red[db][wave][lane * 2]     = sx0 + sx1;
        red[db][wave][lane * 2 + 1] = sy0 + sy1;
        __syncthreads();
        if (tid < 128)
            out[t * 128 + tid] = red[db][0][tid] + red[db][1][tid]
                               + red[db][2][tid] + red[db][3][tid];
        cur0 = nx0; cur1 = nx1;
    }
}

// Sum the 8 j-group partials and decode: ypred[b][t][16]. One wave per (t,b).
__global__ __launch_bounds__(64) void decode_kernel(
    const float* __restrict__ scratch, const float* __restrict__ C_W,
    float* __restrict__ ypred) {
    const int t = blockIdx.x, b = blockIdx.y, l = threadIdx.x;
    __shared__ float S[128];
    float s0 = 0.f, s1 = 0.f;
    #pragma unroll
    for (int jg = 0; jg < 8; jg++) {
        float2 v = *reinterpret_cast<const float2*>(
            scratch + ((size_t)(b * 8 + jg) * 63 + t) * 128 + l * 2);
        s0 += v.x; s1 += v.y;
    }
    S[l * 2] = s0; S[l * 2 + 1] = s1;
    __syncthreads();
    const int o = l >> 2, q = l & 3;
    float acc = 0.f;
    #pragma unroll
    for (int i = 0; i < 32; i++)
        acc += S[q * 32 + i] * C_W[o * 128 + q * 32 + i];
    acc += __shfl_xor(acc, 2, 4);
    acc += __shfl_xor(acc, 1, 4);
    if (q == 0) ypred[(b * 63 + t) * 16 + o] = acc;
}

// ---------------------------------------------------------------------------
extern "C" void kernel_launch(void* const* d_in, const int* in_sizes, int n_in,
                              void* d_out, int out_size, void* d_ws, size_t ws_size,
                              hipStream_t stream) {
    const float* xs      = (const float*)d_in[0];
    const float* us      = (const float*)d_in[1];
    const float* x_gamma = (const float*)d_in[2];
    const float* x_beta  = (const float*)d_in[3];
    const float* xW1     = (const float*)d_in[4];
    const float* xb1     = (const float*)d_in[5];
    const float* xW2     = (const float*)d_in[6];
    const float* xb2     = (const float*)d_in[7];
    const float* xW3     = (const float*)d_in[8];
    const float* x_scale = (const float*)d_in[9];
    const float* u_gamma = (const float*)d_in[10];
    const float* u_beta  = (const float*)d_in[11];
    const float* uW1     = (const float*)d_in[12];
    const float* ub1     = (const float*)d_in[13];
    const float* uW2     = (const float*)d_in[14];
    const float* ub2     = (const float*)d_in[15];
    const float* uW3     = (const float*)d_in[16];
    const float* u_scale = (const float*)d_in[17];
    const float* reL     = (const float*)d_in[18];
    const float* imL     = (const float*)d_in[19];
    const float* C_W     = (const float*)d_in[20];

    char* ws = (char*)d_ws;
    size_t off = 0;
    auto alloc = [&](size_t bytes) -> char* {
        char* p = ws + off;
        off += (bytes + 255) & ~(size_t)255;
        return p;
    };
    float*  part = (float*)alloc(96 * 32 * 4);
    bf16_t* xW1t = (bf16_t*)alloc((size_t)64 * 256 * 32 * 2);
    float*  xb1p = (float*) alloc((size_t)64 * 256 * 4);
    bf16_t* xW2t = (bf16_t*)alloc((size_t)64 * 256 * 256 * 2);
    bf16_t* xW3t = (bf16_t*)alloc((size_t)64 * 128 * 256 * 2);
    bf16_t* uW1t = (bf16_t*)alloc((size_t)64 * 256 * 32 * 2);
    float*  ub1p = (float*) alloc((size_t)64 * 256 * 4);
    bf16_t* uW2t = (bf16_t*)alloc((size_t)64 * 256 * 256 * 2);
    bf16_t* uW3t = (bf16_t*)alloc((size_t)64 * 128 * 256 * 2);
    float*  psi0 = (float*) alloc((size_t)64 * 128 * 4);
    bf16_t* phi  = (bf16_t*)alloc((size_t)64 * 4096 * 128 * 2);   // [j][m][128]
    bf16_t* psiu = (bf16_t*)alloc((size_t)64 * 4032 * 128 * 2);   // [j][m][128]
    float*  scr  = (float*) alloc((size_t)512 * 63 * 128 * 4);    // scan partials

    float* y_out     = (float*)d_out;
    float* ypred_out = y_out + 64 * 63 * 16;

    prep_all_kernel<<<12576, 256, 0, stream>>>(
        xW1, xb1, x_gamma, x_beta, uW1, ub1, u_gamma, u_beta,
        xW2, uW2, xW3, uW3, x_scale, u_scale, ub2, xs, us,
        xW1t, xb1p, uW1t, ub1p, xW2t, uW2t, xW3t, uW3t, psi0, part);
    fused_mlp_kernel<<<4096, 512, 0, stream>>>(
        xs, us, part,
        xW1t, xb1p, xW2t, xb2, xW3t, uW1t, ub1p, uW2t, ub2, uW3t, phi, psiu);
    y_kernel<<<256, 256, 0, stream>>>(phi, C_W, y_out);
    scan_kernel<<<512, 256, 0, stream>>>(phi, psiu, psi0, reL, imL, scr);
    decode_kernel<<<dim3(63, 64), 64, 0, stream>>>(scr, C_W, ypred_out);
}